// Round 1
// baseline (422.970 us; speedup 1.0000x reference)
//
#include <hip/hip_runtime.h>
#include <math.h>

#define LOG2E 1.4426950408889634f

// ---------------------------------------------------------------------------
// Kernel 1: per-image CNN (conv+relu+pool x2, conv+relu+mean) + MLP head.
// One block (256 threads) per image. All intermediates in LDS with zero-padded
// halos so conv loops need no bounds checks. Conv weights are read with
// block-uniform addresses -> compiler emits s_load (scalar K$), keeping the
// VALU pipe for FMAs.
// Outputs per image: g[16], q[16], k[16] into workspace.
// ---------------------------------------------------------------------------
__global__ __launch_bounds__(256) void k_cnn(
    const float* __restrict__ x,                                   // [B][1][32][32]
    const float* __restrict__ w1, const float* __restrict__ b1,    // [8][1][3][3],[8]
    const float* __restrict__ w2, const float* __restrict__ b2,    // [16][8][3][3],[16]
    const float* __restrict__ w3, const float* __restrict__ b3,    // [32][16][3][3],[32]
    const float* __restrict__ gw1,                                 // [32][32]
    const float* __restrict__ gw2,                                 // [16][32]
    const float* __restrict__ rot,                                 // [4][4]
    float* __restrict__ g_out, float* __restrict__ q_out, float* __restrict__ k_out)
{
    __shared__ float xs[34 * 34];        // padded input
    __shared__ float p1[8 * 18 * 18];    // padded pool1 output (8x16x16 interior)
    __shared__ float p2[16 * 10 * 10];   // padded pool2 output (16x8x8 interior)
    __shared__ float fs[32];
    __shared__ float as[32];
    __shared__ float gs[16];

    const int t = threadIdx.x;
    const int b = blockIdx.x;

    // zero LDS (provides zero halo = SAME padding)
    for (int i = t; i < 34 * 34; i += 256) xs[i] = 0.f;
    for (int i = t; i < 8 * 18 * 18; i += 256) p1[i] = 0.f;
    for (int i = t; i < 16 * 10 * 10; i += 256) p2[i] = 0.f;
    __syncthreads();

    // load image interior: thread t loads 4 consecutive floats
    {
        const float4 v = ((const float4*)(x + (size_t)b * 1024))[t];
        const int row = t >> 3;          // (4t)/32
        const int col = (t & 7) << 2;    // (4t)%32
        float* dst = &xs[(row + 1) * 34 + col + 1];
        dst[0] = v.x; dst[1] = v.y; dst[2] = v.z; dst[3] = v.w;
    }
    __syncthreads();

    // ---- stage 1: conv1(1->8) + relu + maxpool2 -> p1 interior 8x16x16 ----
    {
        const int px = t & 15, py = t >> 4;   // pooled position
        float pa[4][4];
        #pragma unroll
        for (int iy = 0; iy < 4; ++iy)
            #pragma unroll
            for (int ix = 0; ix < 4; ++ix)
                pa[iy][ix] = xs[(2 * py + iy) * 34 + (2 * px + ix)];

        #pragma unroll
        for (int oc = 0; oc < 8; ++oc) {
            float mx = -1e30f;
            #pragma unroll
            for (int sy = 0; sy < 2; ++sy)
                #pragma unroll
                for (int sx = 0; sx < 2; ++sx) {
                    float s = b1[oc];
                    #pragma unroll
                    for (int ky = 0; ky < 3; ++ky)
                        #pragma unroll
                        for (int kx = 0; kx < 3; ++kx)
                            s = fmaf(pa[sy + ky][sx + kx], w1[oc * 9 + ky * 3 + kx], s);
                    mx = fmaxf(mx, s);
                }
            p1[oc * 324 + (py + 1) * 18 + (px + 1)] = fmaxf(mx, 0.f);
        }
    }
    __syncthreads();

    // ---- stage 2: conv2(8->16) + relu + maxpool2 -> p2 interior 16x8x8 ----
    {
        const int x2 = t & 15, y2 = t >> 4;   // conv position (one per thread)
        float acc[16];
        #pragma unroll
        for (int oc = 0; oc < 16; ++oc) acc[oc] = b2[oc];

        for (int ic = 0; ic < 8; ++ic) {
            float pt[9];
            #pragma unroll
            for (int ky = 0; ky < 3; ++ky)
                #pragma unroll
                for (int kx = 0; kx < 3; ++kx)
                    pt[ky * 3 + kx] = p1[ic * 324 + (y2 + ky) * 18 + (x2 + kx)];
            #pragma unroll
            for (int oc = 0; oc < 16; ++oc) {
                float s = acc[oc];
                #pragma unroll
                for (int k = 0; k < 9; ++k)
                    s = fmaf(pt[k], w2[oc * 72 + ic * 9 + k], s);
                acc[oc] = s;
            }
        }
        // relu + 2x2 max pool across lanes {t, t^1, t^16, t^17} (same wave)
        #pragma unroll
        for (int oc = 0; oc < 16; ++oc) {
            float v = fmaxf(acc[oc], 0.f);
            v = fmaxf(v, __shfl_xor(v, 1));
            v = fmaxf(v, __shfl_xor(v, 16));
            if (((t & 1) == 0) && ((t & 16) == 0))
                p2[oc * 100 + ((y2 >> 1) + 1) * 10 + ((x2 >> 1) + 1)] = v;
        }
    }
    __syncthreads();

    // ---- stage 3: conv3(16->32) + relu + spatial mean -> fs[32] ----
    {
        const int wv = __builtin_amdgcn_readfirstlane(t >> 6);  // wave id 0..3 -> oc block
        const int ln = t & 63;
        const int x3 = ln & 7, y3 = ln >> 3;   // conv position 8x8
        float a3[8];
        #pragma unroll
        for (int o = 0; o < 8; ++o) a3[o] = b3[wv * 8 + o];

        for (int ic = 0; ic < 16; ++ic) {
            float pt[9];
            #pragma unroll
            for (int ky = 0; ky < 3; ++ky)
                #pragma unroll
                for (int kx = 0; kx < 3; ++kx)
                    pt[ky * 3 + kx] = p2[ic * 100 + (y3 + ky) * 10 + (x3 + kx)];
            #pragma unroll
            for (int o = 0; o < 8; ++o) {
                float s = a3[o];
                #pragma unroll
                for (int k = 0; k < 9; ++k)
                    s = fmaf(pt[k], w3[(wv * 8 + o) * 144 + ic * 9 + k], s);
                a3[o] = s;
            }
        }
        #pragma unroll
        for (int o = 0; o < 8; ++o) {
            float v = fmaxf(a3[o], 0.f);
            #pragma unroll
            for (int off = 32; off; off >>= 1) v += __shfl_xor(v, off);
            if (ln == 0) fs[wv * 8 + o] = v * (1.f / 64.f);
        }
    }
    __syncthreads();

    // ---- stage 4: MLP head: a=tanh(W1@f), g=tanh(W2@a), q=G@R, k=G@R^T ----
    if (t < 32) {
        float s = 0.f;
        #pragma unroll
        for (int j = 0; j < 32; ++j) s = fmaf(gw1[t * 32 + j], fs[j], s);
        as[t] = tanhf(s);
    }
    __syncthreads();
    if (t < 16) {
        float s = 0.f;
        #pragma unroll
        for (int j = 0; j < 32; ++j) s = fmaf(gw2[t * 32 + j], as[j], s);
        gs[t] = tanhf(s);
    }
    __syncthreads();
    if (t < 16) {
        const int r = t >> 2, c = t & 3;
        float qv = 0.f, kv = 0.f;
        #pragma unroll
        for (int j = 0; j < 4; ++j) {
            qv = fmaf(gs[r * 4 + j], rot[j * 4 + c], qv);   // G @ R
            kv = fmaf(gs[r * 4 + j], rot[c * 4 + j], kv);   // G @ R^T
        }
        g_out[b * 16 + t] = gs[t];
        q_out[b * 16 + t] = qv;
        k_out[b * 16 + t] = kv;
    }
}

// ---------------------------------------------------------------------------
// Kernel 2: attention over the batch. One wave per row (online softmax over
// 4096 cols, k/g L2-resident), fused reduce_w/cls_w epilogue -> out_pre[B][2].
// ---------------------------------------------------------------------------
__global__ __launch_bounds__(256) void k_attn(
    const float* __restrict__ qg, const float* __restrict__ kg,
    const float* __restrict__ gg, const float* __restrict__ ent,
    const float* __restrict__ rw, const float* __restrict__ rb,
    const float* __restrict__ cw, const float* __restrict__ cb,
    float* __restrict__ outp, int B)
{
    const int lane = threadIdx.x & 63;
    const int r = __builtin_amdgcn_readfirstlane(blockIdx.x * 4 + (threadIdx.x >> 6));

    const float temp = (cosf(ent[0]) + cosf(ent[1]) + cosf(ent[2])) * (1.f / 3.f);
    const float scale = temp * 0.25f;   // temp / sqrt(16)

    // q row is wave-uniform -> scalar loads; pre-fold scale into q
    float qv[16];
    #pragma unroll
    for (int j = 0; j < 16; ++j) qv[j] = qg[r * 16 + j] * scale;

    float m = -1e30f, l = 0.f;
    float acc[16];
    #pragma unroll
    for (int j = 0; j < 16; ++j) acc[j] = 0.f;

    for (int c0 = 0; c0 < B; c0 += 64) {
        const int col = c0 + lane;
        const float4* kp = (const float4*)(kg + (size_t)col * 16);
        const float4 k0 = kp[0], k1 = kp[1], k2 = kp[2], k3 = kp[3];
        float s;
        s = qv[0] * k0.x;            s = fmaf(qv[1], k0.y, s);
        s = fmaf(qv[2], k0.z, s);    s = fmaf(qv[3], k0.w, s);
        s = fmaf(qv[4], k1.x, s);    s = fmaf(qv[5], k1.y, s);
        s = fmaf(qv[6], k1.z, s);    s = fmaf(qv[7], k1.w, s);
        s = fmaf(qv[8], k2.x, s);    s = fmaf(qv[9], k2.y, s);
        s = fmaf(qv[10], k2.z, s);   s = fmaf(qv[11], k2.w, s);
        s = fmaf(qv[12], k3.x, s);   s = fmaf(qv[13], k3.y, s);
        s = fmaf(qv[14], k3.z, s);   s = fmaf(qv[15], k3.w, s);

        const float mn = fmaxf(m, s);
        if (__ballot(mn > m)) {      // rescale only when some lane's max moved
            const float corr = exp2f((m - mn) * LOG2E);
            l *= corr;
            #pragma unroll
            for (int j = 0; j < 16; ++j) acc[j] *= corr;
            m = mn;
        }
        const float e = exp2f((s - m) * LOG2E);
        l += e;

        const float4* gp = (const float4*)(gg + (size_t)col * 16);
        const float4 g0 = gp[0], g1 = gp[1], g2 = gp[2], g3 = gp[3];
        acc[0]  = fmaf(e, g0.x, acc[0]);   acc[1]  = fmaf(e, g0.y, acc[1]);
        acc[2]  = fmaf(e, g0.z, acc[2]);   acc[3]  = fmaf(e, g0.w, acc[3]);
        acc[4]  = fmaf(e, g1.x, acc[4]);   acc[5]  = fmaf(e, g1.y, acc[5]);
        acc[6]  = fmaf(e, g1.z, acc[6]);   acc[7]  = fmaf(e, g1.w, acc[7]);
        acc[8]  = fmaf(e, g2.x, acc[8]);   acc[9]  = fmaf(e, g2.y, acc[9]);
        acc[10] = fmaf(e, g2.z, acc[10]);  acc[11] = fmaf(e, g2.w, acc[11]);
        acc[12] = fmaf(e, g3.x, acc[12]);  acc[13] = fmaf(e, g3.y, acc[13]);
        acc[14] = fmaf(e, g3.z, acc[14]);  acc[15] = fmaf(e, g3.w, acc[15]);
    }

    // merge the 64 per-lane online-softmax states (butterfly)
    #pragma unroll
    for (int off = 1; off < 64; off <<= 1) {
        const float m2 = __shfl_xor(m, off);
        const float l2 = __shfl_xor(l, off);
        const float mn = fmaxf(m, m2);
        const float ca = exp2f((m - mn) * LOG2E);
        const float cb2 = exp2f((m2 - mn) * LOG2E);
        l = l * ca + l2 * cb2;
        #pragma unroll
        for (int j = 0; j < 16; ++j)
            acc[j] = acc[j] * ca + __shfl_xor(acc[j], off) * cb2;
        m = mn;
    }

    if (lane == 0) {
        const float il = 1.f / l;
        float red[2];
        #pragma unroll
        for (int c = 0; c < 2; ++c) {
            float s = rb[c];
            #pragma unroll
            for (int j = 0; j < 16; ++j) s = fmaf(gg[r * 16 + j], rw[c * 32 + j], s);
            #pragma unroll
            for (int j = 0; j < 16; ++j) s = fmaf(acc[j] * il, rw[c * 32 + 16 + j], s);
            red[c] = s;
        }
        // fraud layers with all-zero params are the identity; classifier:
        outp[r * 2 + 0] = cb[0] + cw[0] * red[0] + cw[1] * red[1];
        outp[r * 2 + 1] = cb[1] + cw[2] * red[0] + cw[3] * red[1];
    }
}

// ---------------------------------------------------------------------------
// Kernel 3: BatchNorm1d(2) with batch stats (biased var), in-place on d_out.
// Single block; 8192 floats is tiny.
// ---------------------------------------------------------------------------
__global__ __launch_bounds__(1024) void k_bn(
    float* __restrict__ data, const float* __restrict__ gamma,
    const float* __restrict__ beta, int B)
{
    __shared__ float red[16][4];
    __shared__ float coef[4];
    const int t = threadIdx.x;
    float s0 = 0.f, s1 = 0.f, q0 = 0.f, q1 = 0.f;
    for (int i = t; i < B; i += 1024) {
        const float2 v = ((const float2*)data)[i];
        s0 += v.x; q0 += v.x * v.x;
        s1 += v.y; q1 += v.y * v.y;
    }
    #pragma unroll
    for (int off = 32; off; off >>= 1) {
        s0 += __shfl_xor(s0, off); q0 += __shfl_xor(q0, off);
        s1 += __shfl_xor(s1, off); q1 += __shfl_xor(q1, off);
    }
    if ((t & 63) == 0) {
        red[t >> 6][0] = s0; red[t >> 6][1] = q0;
        red[t >> 6][2] = s1; red[t >> 6][3] = q1;
    }
    __syncthreads();
    if (t == 0) {
        float S0 = 0.f, Q0 = 0.f, S1 = 0.f, Q1 = 0.f;
        for (int w = 0; w < 16; ++w) {
            S0 += red[w][0]; Q0 += red[w][1]; S1 += red[w][2]; Q1 += red[w][3];
        }
        const float inv = 1.f / (float)B;
        const float mu0 = S0 * inv, mu1 = S1 * inv;
        const float v0 = Q0 * inv - mu0 * mu0;
        const float v1 = Q1 * inv - mu1 * mu1;
        const float sc0 = gamma[0] * rsqrtf(v0 + 1e-5f);
        const float sc1 = gamma[1] * rsqrtf(v1 + 1e-5f);
        coef[0] = sc0; coef[1] = beta[0] - mu0 * sc0;
        coef[2] = sc1; coef[3] = beta[1] - mu1 * sc1;
    }
    __syncthreads();
    const float sc0 = coef[0], sh0 = coef[1], sc1 = coef[2], sh1 = coef[3];
    for (int i = t; i < B; i += 1024) {
        float2 v = ((const float2*)data)[i];
        v.x = fmaf(v.x, sc0, sh0);
        v.y = fmaf(v.y, sc1, sh1);
        ((float2*)data)[i] = v;
    }
}

extern "C" void kernel_launch(void* const* d_in, const int* in_sizes, int n_in,
                              void* d_out, int out_size, void* d_ws, size_t ws_size,
                              hipStream_t stream)
{
    (void)n_in; (void)out_size; (void)ws_size;
    const float* x   = (const float*)d_in[0];
    const float* w1  = (const float*)d_in[1];
    const float* b1  = (const float*)d_in[2];
    const float* w2  = (const float*)d_in[3];
    const float* b2  = (const float*)d_in[4];
    const float* w3  = (const float*)d_in[5];
    const float* b3  = (const float*)d_in[6];
    const float* gw1 = (const float*)d_in[7];
    const float* gw2 = (const float*)d_in[8];
    const float* rot = (const float*)d_in[9];
    const float* ent = (const float*)d_in[10];
    const float* rw  = (const float*)d_in[11];
    const float* rbv = (const float*)d_in[12];
    const float* cw  = (const float*)d_in[13];
    const float* cbv = (const float*)d_in[14];
    const float* gam = (const float*)d_in[15];
    const float* bet = (const float*)d_in[16];

    const int B = in_sizes[0] / (32 * 32);   // 4096

    float* ws    = (float*)d_ws;
    float* g_buf = ws;              // B*16
    float* q_buf = ws + (size_t)B * 16;
    float* k_buf = ws + (size_t)B * 32;
    float* pre   = (float*)d_out;   // [B][2], normalized in place by k_bn

    k_cnn<<<B, 256, 0, stream>>>(x, w1, b1, w2, b2, w3, b3, gw1, gw2, rot,
                                 g_buf, q_buf, k_buf);
    k_attn<<<B / 4, 256, 0, stream>>>(q_buf, k_buf, g_buf, ent, rw, rbv, cw, cbv,
                                      pre, B);
    k_bn<<<1, 1024, 0, stream>>>(pre, gam, bet, B);
}

// Round 2
// 349.310 us; speedup vs baseline: 1.2109x; 1.2109x over previous
//
#include <hip/hip_runtime.h>
#include <math.h>

#define LOG2E 1.4426950408889634f

__device__ __forceinline__ float fast_tanh(float x) {
    // tanh(x) = (e^2x - 1)/(e^2x + 1); clamp so exp2 never overflows.
    const float xc = fminf(fmaxf(x, -15.f), 15.f);
    const float t = exp2f(xc * (2.f * LOG2E));
    return (t - 1.f) * __builtin_amdgcn_rcpf(t + 1.f);
}

// ---------------------------------------------------------------------------
// Kernel 1: per-image CNN (conv+relu+pool x2, conv+relu+mean) + MLP head.
// One block (256 threads) per image. Zero-padded LDS halos, block-uniform
// weight reads. Outputs per image: g[16], q[16], k[16].
// ---------------------------------------------------------------------------
__global__ __launch_bounds__(256) void k_cnn(
    const float* __restrict__ x,
    const float* __restrict__ w1, const float* __restrict__ b1,
    const float* __restrict__ w2, const float* __restrict__ b2,
    const float* __restrict__ w3, const float* __restrict__ b3,
    const float* __restrict__ gw1,
    const float* __restrict__ gw2,
    const float* __restrict__ rot,
    float* __restrict__ g_out, float* __restrict__ q_out, float* __restrict__ k_out)
{
    __shared__ float xs[34 * 34];
    __shared__ float p1[8 * 18 * 18];
    __shared__ float p2[16 * 10 * 10];
    __shared__ float fs[32];
    __shared__ float as[32];
    __shared__ float gs[16];

    const int t = threadIdx.x;
    const int b = blockIdx.x;

    for (int i = t; i < 34 * 34; i += 256) xs[i] = 0.f;
    for (int i = t; i < 8 * 18 * 18; i += 256) p1[i] = 0.f;
    for (int i = t; i < 16 * 10 * 10; i += 256) p2[i] = 0.f;
    __syncthreads();

    {
        const float4 v = ((const float4*)(x + (size_t)b * 1024))[t];
        const int row = t >> 3;
        const int col = (t & 7) << 2;
        float* dst = &xs[(row + 1) * 34 + col + 1];
        dst[0] = v.x; dst[1] = v.y; dst[2] = v.z; dst[3] = v.w;
    }
    __syncthreads();

    // ---- stage 1: conv1(1->8) + relu + maxpool2 ----
    {
        const int px = t & 15, py = t >> 4;
        float pa[4][4];
        #pragma unroll
        for (int iy = 0; iy < 4; ++iy)
            #pragma unroll
            for (int ix = 0; ix < 4; ++ix)
                pa[iy][ix] = xs[(2 * py + iy) * 34 + (2 * px + ix)];

        #pragma unroll
        for (int oc = 0; oc < 8; ++oc) {
            float mx = -1e30f;
            #pragma unroll
            for (int sy = 0; sy < 2; ++sy)
                #pragma unroll
                for (int sx = 0; sx < 2; ++sx) {
                    float s = b1[oc];
                    #pragma unroll
                    for (int ky = 0; ky < 3; ++ky)
                        #pragma unroll
                        for (int kx = 0; kx < 3; ++kx)
                            s = fmaf(pa[sy + ky][sx + kx], w1[oc * 9 + ky * 3 + kx], s);
                    mx = fmaxf(mx, s);
                }
            p1[oc * 324 + (py + 1) * 18 + (px + 1)] = fmaxf(mx, 0.f);
        }
    }
    __syncthreads();

    // ---- stage 2: conv2(8->16) + relu + maxpool2 ----
    {
        const int x2 = t & 15, y2 = t >> 4;
        float acc[16];
        #pragma unroll
        for (int oc = 0; oc < 16; ++oc) acc[oc] = b2[oc];

        for (int ic = 0; ic < 8; ++ic) {
            float pt[9];
            #pragma unroll
            for (int ky = 0; ky < 3; ++ky)
                #pragma unroll
                for (int kx = 0; kx < 3; ++kx)
                    pt[ky * 3 + kx] = p1[ic * 324 + (y2 + ky) * 18 + (x2 + kx)];
            #pragma unroll
            for (int oc = 0; oc < 16; ++oc) {
                float s = acc[oc];
                #pragma unroll
                for (int k = 0; k < 9; ++k)
                    s = fmaf(pt[k], w2[oc * 72 + ic * 9 + k], s);
                acc[oc] = s;
            }
        }
        #pragma unroll
        for (int oc = 0; oc < 16; ++oc) {
            float v = fmaxf(acc[oc], 0.f);
            v = fmaxf(v, __shfl_xor(v, 1));
            v = fmaxf(v, __shfl_xor(v, 16));
            if (((t & 1) == 0) && ((t & 16) == 0))
                p2[oc * 100 + ((y2 >> 1) + 1) * 10 + ((x2 >> 1) + 1)] = v;
        }
    }
    __syncthreads();

    // ---- stage 3: conv3(16->32) + relu + spatial mean ----
    {
        const int wv = __builtin_amdgcn_readfirstlane(t >> 6);
        const int ln = t & 63;
        const int x3 = ln & 7, y3 = ln >> 3;
        float a3[8];
        #pragma unroll
        for (int o = 0; o < 8; ++o) a3[o] = b3[wv * 8 + o];

        for (int ic = 0; ic < 16; ++ic) {
            float pt[9];
            #pragma unroll
            for (int ky = 0; ky < 3; ++ky)
                #pragma unroll
                for (int kx = 0; kx < 3; ++kx)
                    pt[ky * 3 + kx] = p2[ic * 100 + (y3 + ky) * 10 + (x3 + kx)];
            #pragma unroll
            for (int o = 0; o < 8; ++o) {
                float s = a3[o];
                #pragma unroll
                for (int k = 0; k < 9; ++k)
                    s = fmaf(pt[k], w3[(wv * 8 + o) * 144 + ic * 9 + k], s);
                a3[o] = s;
            }
        }
        #pragma unroll
        for (int o = 0; o < 8; ++o) {
            float v = fmaxf(a3[o], 0.f);
            #pragma unroll
            for (int off = 32; off; off >>= 1) v += __shfl_xor(v, off);
            if (ln == 0) fs[wv * 8 + o] = v * (1.f / 64.f);
        }
    }
    __syncthreads();

    // ---- stage 4: MLP head ----
    if (t < 32) {
        float s = 0.f;
        #pragma unroll
        for (int j = 0; j < 32; ++j) s = fmaf(gw1[t * 32 + j], fs[j], s);
        as[t] = fast_tanh(s);
    }
    __syncthreads();
    if (t < 16) {
        float s = 0.f;
        #pragma unroll
        for (int j = 0; j < 32; ++j) s = fmaf(gw2[t * 32 + j], as[j], s);
        gs[t] = fast_tanh(s);
    }
    __syncthreads();
    if (t < 16) {
        const int r = t >> 2, c = t & 3;
        float qv = 0.f, kv = 0.f;
        #pragma unroll
        for (int j = 0; j < 4; ++j) {
            qv = fmaf(gs[r * 4 + j], rot[j * 4 + c], qv);
            kv = fmaf(gs[r * 4 + j], rot[c * 4 + j], kv);
        }
        g_out[b * 16 + t] = gs[t];
        q_out[b * 16 + t] = qv;
        k_out[b * 16 + t] = kv;
    }
}

// ---------------------------------------------------------------------------
// Kernel 2 v2: 4 rows per BLOCK (q block-uniform); each of the 4 waves covers
// a quarter of the columns for all 4 rows -> every k/g column load (L2-hit)
// feeds 4 rows. Lane-butterfly + LDS cross-wave merge of the online-softmax
// states; fused reduce/cls epilogue.
// ---------------------------------------------------------------------------
__global__ __launch_bounds__(256) void k_attn(
    const float* __restrict__ qg, const float* __restrict__ kg,
    const float* __restrict__ gg, const float* __restrict__ ent,
    const float* __restrict__ rw, const float* __restrict__ rb,
    const float* __restrict__ cw, const float* __restrict__ cb,
    float* __restrict__ outp, int B)
{
    __shared__ float red[4][4][20];   // [wave][row][m, l, pad, pad, acc0..15]

    const int t = threadIdx.x;
    const int lane = t & 63;
    const int w = t >> 6;
    const int r0 = blockIdx.x * 4;

    const float temp = (cosf(ent[0]) + cosf(ent[1]) + cosf(ent[2])) * (1.f / 3.f);
    const float scale = temp * 0.25f;   // temp / sqrt(16)

    float q[4][16];
    #pragma unroll
    for (int r = 0; r < 4; ++r)
        #pragma unroll
        for (int j = 0; j < 16; ++j)
            q[r][j] = qg[(r0 + r) * 16 + j] * scale;   // block-uniform

    float m[4], l[4], acc[4][16];
    #pragma unroll
    for (int r = 0; r < 4; ++r) {
        m[r] = -1e30f; l[r] = 0.f;
        #pragma unroll
        for (int j = 0; j < 16; ++j) acc[r][j] = 0.f;
    }

    const int iters = B >> 8;   // 16 for B=4096
    for (int i = 0; i < iters; ++i) {
        const int col = i * 256 + w * 64 + lane;

        const float4* kp = (const float4*)(kg + (size_t)col * 16);
        const float4 ka = kp[0], kb = kp[1], kc = kp[2], kd = kp[3];
        const float kv[16] = {ka.x, ka.y, ka.z, ka.w, kb.x, kb.y, kb.z, kb.w,
                              kc.x, kc.y, kc.z, kc.w, kd.x, kd.y, kd.z, kd.w};

        float s[4];
        #pragma unroll
        for (int r = 0; r < 4; ++r) {
            float sv = q[r][0] * kv[0];
            #pragma unroll
            for (int j = 1; j < 16; ++j) sv = fmaf(q[r][j], kv[j], sv);
            s[r] = sv;
        }

        float mn[4];
        bool ch = false;
        #pragma unroll
        for (int r = 0; r < 4; ++r) {
            mn[r] = fmaxf(m[r], s[r]);
            ch = ch | (mn[r] > m[r]);
        }
        if (__ballot(ch)) {
            #pragma unroll
            for (int r = 0; r < 4; ++r) {
                const float corr = exp2f((m[r] - mn[r]) * LOG2E);
                l[r] *= corr;
                #pragma unroll
                for (int j = 0; j < 16; ++j) acc[r][j] *= corr;
                m[r] = mn[r];
            }
        }

        float e[4];
        #pragma unroll
        for (int r = 0; r < 4; ++r) {
            e[r] = exp2f((s[r] - m[r]) * LOG2E);
            l[r] += e[r];
        }

        const float4* gp = (const float4*)(gg + (size_t)col * 16);
        const float4 ga = gp[0], gb = gp[1], gc = gp[2], gd = gp[3];
        const float gv[16] = {ga.x, ga.y, ga.z, ga.w, gb.x, gb.y, gb.z, gb.w,
                              gc.x, gc.y, gc.z, gc.w, gd.x, gd.y, gd.z, gd.w};
        #pragma unroll
        for (int r = 0; r < 4; ++r)
            #pragma unroll
            for (int j = 0; j < 16; ++j)
                acc[r][j] = fmaf(e[r], gv[j], acc[r][j]);
    }

    // ---- merge 64 lanes within the wave ----
    #pragma unroll
    for (int r = 0; r < 4; ++r) {
        const float mo = m[r];
        float mm = mo;
        #pragma unroll
        for (int off = 1; off < 64; off <<= 1) mm = fmaxf(mm, __shfl_xor(mm, off));
        const float f = exp2f((mo - mm) * LOG2E);
        m[r] = mm;
        l[r] *= f;
        #pragma unroll
        for (int j = 0; j < 16; ++j) acc[r][j] *= f;
        #pragma unroll
        for (int off = 1; off < 64; off <<= 1) {
            l[r] += __shfl_xor(l[r], off);
            #pragma unroll
            for (int j = 0; j < 16; ++j) acc[r][j] += __shfl_xor(acc[r][j], off);
        }
    }

    if (lane == 0) {
        #pragma unroll
        for (int r = 0; r < 4; ++r) {
            red[w][r][0] = m[r];
            red[w][r][1] = l[r];
            #pragma unroll
            for (int j = 0; j < 16; ++j) red[w][r][4 + j] = acc[r][j];
        }
    }
    __syncthreads();

    // ---- cross-wave merge + epilogue: threads 0..3, one row each ----
    if (t < 4) {
        const int r = t;
        const int row = r0 + r;
        float M = red[0][r][0];
        for (int ww = 1; ww < 4; ++ww) M = fmaxf(M, red[ww][r][0]);
        float L = 0.f, A[16];
        #pragma unroll
        for (int j = 0; j < 16; ++j) A[j] = 0.f;
        for (int ww = 0; ww < 4; ++ww) {
            const float c = exp2f((red[ww][r][0] - M) * LOG2E);
            L = fmaf(red[ww][r][1], c, L);
            #pragma unroll
            for (int j = 0; j < 16; ++j) A[j] = fmaf(red[ww][r][4 + j], c, A[j]);
        }
        const float il = 1.f / L;

        float redv[2];
        #pragma unroll
        for (int c = 0; c < 2; ++c) {
            float sv = rb[c];
            #pragma unroll
            for (int j = 0; j < 16; ++j) sv = fmaf(gg[row * 16 + j], rw[c * 32 + j], sv);
            #pragma unroll
            for (int j = 0; j < 16; ++j) sv = fmaf(A[j] * il, rw[c * 32 + 16 + j], sv);
            redv[c] = sv;
        }
        // fraud layers (all-zero params) are the identity; classifier:
        outp[row * 2 + 0] = cb[0] + cw[0] * redv[0] + cw[1] * redv[1];
        outp[row * 2 + 1] = cb[1] + cw[2] * redv[0] + cw[3] * redv[1];
    }
}

// ---------------------------------------------------------------------------
// Kernel 3: BatchNorm1d(2), batch stats, in-place on d_out.
// ---------------------------------------------------------------------------
__global__ __launch_bounds__(1024) void k_bn(
    float* __restrict__ data, const float* __restrict__ gamma,
    const float* __restrict__ beta, int B)
{
    __shared__ float red[16][4];
    __shared__ float coef[4];
    const int t = threadIdx.x;
    float s0 = 0.f, s1 = 0.f, q0 = 0.f, q1 = 0.f;
    for (int i = t; i < B; i += 1024) {
        const float2 v = ((const float2*)data)[i];
        s0 += v.x; q0 += v.x * v.x;
        s1 += v.y; q1 += v.y * v.y;
    }
    #pragma unroll
    for (int off = 32; off; off >>= 1) {
        s0 += __shfl_xor(s0, off); q0 += __shfl_xor(q0, off);
        s1 += __shfl_xor(s1, off); q1 += __shfl_xor(q1, off);
    }
    if ((t & 63) == 0) {
        red[t >> 6][0] = s0; red[t >> 6][1] = q0;
        red[t >> 6][2] = s1; red[t >> 6][3] = q1;
    }
    __syncthreads();
    if (t == 0) {
        float S0 = 0.f, Q0 = 0.f, S1 = 0.f, Q1 = 0.f;
        for (int w = 0; w < 16; ++w) {
            S0 += red[w][0]; Q0 += red[w][1]; S1 += red[w][2]; Q1 += red[w][3];
        }
        const float inv = 1.f / (float)B;
        const float mu0 = S0 * inv, mu1 = S1 * inv;
        const float v0 = Q0 * inv - mu0 * mu0;
        const float v1 = Q1 * inv - mu1 * mu1;
        const float sc0 = gamma[0] * rsqrtf(v0 + 1e-5f);
        const float sc1 = gamma[1] * rsqrtf(v1 + 1e-5f);
        coef[0] = sc0; coef[1] = beta[0] - mu0 * sc0;
        coef[2] = sc1; coef[3] = beta[1] - mu1 * sc1;
    }
    __syncthreads();
    const float sc0 = coef[0], sh0 = coef[1], sc1 = coef[2], sh1 = coef[3];
    for (int i = t; i < B; i += 1024) {
        float2 v = ((const float2*)data)[i];
        v.x = fmaf(v.x, sc0, sh0);
        v.y = fmaf(v.y, sc1, sh1);
        ((float2*)data)[i] = v;
    }
}

extern "C" void kernel_launch(void* const* d_in, const int* in_sizes, int n_in,
                              void* d_out, int out_size, void* d_ws, size_t ws_size,
                              hipStream_t stream)
{
    (void)n_in; (void)out_size; (void)ws_size;
    const float* x   = (const float*)d_in[0];
    const float* w1  = (const float*)d_in[1];
    const float* b1  = (const float*)d_in[2];
    const float* w2  = (const float*)d_in[3];
    const float* b2  = (const float*)d_in[4];
    const float* w3  = (const float*)d_in[5];
    const float* b3  = (const float*)d_in[6];
    const float* gw1 = (const float*)d_in[7];
    const float* gw2 = (const float*)d_in[8];
    const float* rot = (const float*)d_in[9];
    const float* ent = (const float*)d_in[10];
    const float* rw  = (const float*)d_in[11];
    const float* rbv = (const float*)d_in[12];
    const float* cw  = (const float*)d_in[13];
    const float* cbv = (const float*)d_in[14];
    const float* gam = (const float*)d_in[15];
    const float* bet = (const float*)d_in[16];

    const int B = in_sizes[0] / (32 * 32);   // 4096

    float* ws    = (float*)d_ws;
    float* g_buf = ws;
    float* q_buf = ws + (size_t)B * 16;
    float* k_buf = ws + (size_t)B * 32;
    float* pre   = (float*)d_out;

    k_cnn<<<B, 256, 0, stream>>>(x, w1, b1, w2, b2, w3, b3, gw1, gw2, rot,
                                 g_buf, q_buf, k_buf);
    k_attn<<<B / 4, 256, 0, stream>>>(q_buf, k_buf, g_buf, ent, rw, rbv, cw, cbv,
                                      pre, B);
    k_bn<<<1, 1024, 0, stream>>>(pre, gam, bet, B);
}

// Round 4
// 314.345 us; speedup vs baseline: 1.3456x; 1.1112x over previous
//
#include <hip/hip_runtime.h>
#include <math.h>

#define LOG2E 1.4426950408889634f

typedef _Float16 h2 __attribute__((ext_vector_type(2)));

__device__ __forceinline__ h2 pk(float a, float b) {
    return __builtin_bit_cast(h2, __builtin_amdgcn_cvt_pkrtz(a, b));
}

__device__ __forceinline__ float fast_tanh(float x) {
    const float xc = fminf(fmaxf(x, -15.f), 15.f);
    const float t = exp2f(xc * (2.f * LOG2E));
    return (t - 1.f) * __builtin_amdgcn_rcpf(t + 1.f);
}

__device__ __forceinline__ float uniform_f(float x) {
    return __int_as_float(__builtin_amdgcn_readfirstlane(__float_as_int(x)));
}

// ---------------------------------------------------------------------------
// Prelude: pack conv2/conv3 weights into half2 input-channel pairs with
// output-channel-contiguous layout (enables wide uniform s_load in k_cnn).
// ---------------------------------------------------------------------------
__global__ __launch_bounds__(256) void k_pack(
    const float* __restrict__ w2, const float* __restrict__ w3,
    h2* __restrict__ w2p, h2* __restrict__ w3p)
{
    for (int idx = threadIdx.x; idx < 576; idx += 256) {
        const int oc = idx & 15;
        const int k = (idx >> 4) % 9;
        const int icp = idx / 144;
        w2p[idx] = pk(w2[oc * 72 + (2 * icp) * 9 + k],
                      w2[oc * 72 + (2 * icp + 1) * 9 + k]);
    }
    for (int idx = threadIdx.x; idx < 2304; idx += 256) {
        const int o = idx & 7;
        const int k = (idx >> 3) % 9;
        const int rest = idx / 72;           // wv*8 + icp
        const int oc = (rest >> 3) * 8 + o;
        const int icp = rest & 7;
        w3p[idx] = pk(w3[oc * 144 + (2 * icp) * 9 + k],
                      w3[oc * 144 + (2 * icp + 1) * 9 + k]);
    }
}

// ---------------------------------------------------------------------------
// Kernel 1 v3: per-image CNN, conv2/conv3 via v_dot2_f32_f16 (2 MAC/instr,
// fp32 accum). Activations stored in LDS as interleaved channel-pair half2.
// ---------------------------------------------------------------------------
__global__ __launch_bounds__(256) void k_cnn(
    const float* __restrict__ x,
    const float* __restrict__ w1, const float* __restrict__ b1,
    const h2* __restrict__ w2p, const float* __restrict__ b2,
    const h2* __restrict__ w3p, const float* __restrict__ b3,
    const float* __restrict__ gw1,
    const float* __restrict__ gw2,
    const float* __restrict__ rot,
    float* __restrict__ g_out, float* __restrict__ q_out, float* __restrict__ k_out)
{
    __shared__ float xs[34 * 34];
    __shared__ h2 p1h[4 * 18 * 18];   // [icp][18][18], channel pairs
    __shared__ h2 p2h[8 * 10 * 10];   // [icp][10][10]
    __shared__ float fs[32];
    __shared__ float as[32];
    __shared__ float gs[16];

    const int t = threadIdx.x;
    const int b = blockIdx.x;

    for (int i = t; i < 34 * 34; i += 256) xs[i] = 0.f;
    for (int i = t; i < 4 * 324; i += 256) p1h[i] = pk(0.f, 0.f);
    for (int i = t; i < 8 * 100; i += 256) p2h[i] = pk(0.f, 0.f);
    __syncthreads();

    {
        const float4 v = ((const float4*)(x + (size_t)b * 1024))[t];
        const int row = t >> 3;
        const int col = (t & 7) << 2;
        float* dst = &xs[(row + 1) * 34 + col + 1];
        dst[0] = v.x; dst[1] = v.y; dst[2] = v.z; dst[3] = v.w;
    }
    __syncthreads();

    // ---- stage 1: conv1(1->8) fp32 + relu + maxpool2 -> p1h pairs ----
    {
        const int px = t & 15, py = t >> 4;
        float pa[4][4];
        #pragma unroll
        for (int iy = 0; iy < 4; ++iy)
            #pragma unroll
            for (int ix = 0; ix < 4; ++ix)
                pa[iy][ix] = xs[(2 * py + iy) * 34 + (2 * px + ix)];

        float r[8];
        #pragma unroll
        for (int oc = 0; oc < 8; ++oc) {
            float mx = -1e30f;
            #pragma unroll
            for (int sy = 0; sy < 2; ++sy)
                #pragma unroll
                for (int sx = 0; sx < 2; ++sx) {
                    float s = b1[oc];
                    #pragma unroll
                    for (int ky = 0; ky < 3; ++ky)
                        #pragma unroll
                        for (int kx = 0; kx < 3; ++kx)
                            s = fmaf(pa[sy + ky][sx + kx], w1[oc * 9 + ky * 3 + kx], s);
                    mx = fmaxf(mx, s);
                }
            r[oc] = fmaxf(mx, 0.f);
        }
        #pragma unroll
        for (int ocp = 0; ocp < 4; ++ocp)
            p1h[ocp * 324 + (py + 1) * 18 + (px + 1)] = pk(r[2 * ocp], r[2 * ocp + 1]);
    }
    __syncthreads();

    // ---- stage 2: conv2(8->16) via dot2 + relu + maxpool2 -> p2h pairs ----
    {
        const int x2 = t & 15, y2 = t >> 4;
        float acc[16];
        #pragma unroll
        for (int oc = 0; oc < 16; ++oc) acc[oc] = b2[oc];

        #pragma unroll
        for (int icp = 0; icp < 4; ++icp) {
            h2 pt[9];
            #pragma unroll
            for (int ky = 0; ky < 3; ++ky)
                #pragma unroll
                for (int kx = 0; kx < 3; ++kx)
                    pt[ky * 3 + kx] = p1h[icp * 324 + (y2 + ky) * 18 + (x2 + kx)];
            #pragma unroll
            for (int k = 0; k < 9; ++k)
                #pragma unroll
                for (int oc = 0; oc < 16; ++oc)
                    acc[oc] = __builtin_amdgcn_fdot2(pt[k], w2p[(icp * 9 + k) * 16 + oc],
                                                     acc[oc], false);
        }
        #pragma unroll
        for (int ocp = 0; ocp < 8; ++ocp) {
            float v0 = fmaxf(acc[2 * ocp], 0.f);
            float v1 = fmaxf(acc[2 * ocp + 1], 0.f);
            v0 = fmaxf(v0, __shfl_xor(v0, 1));  v0 = fmaxf(v0, __shfl_xor(v0, 16));
            v1 = fmaxf(v1, __shfl_xor(v1, 1));  v1 = fmaxf(v1, __shfl_xor(v1, 16));
            if (((t & 1) == 0) && ((t & 16) == 0))
                p2h[ocp * 100 + ((y2 >> 1) + 1) * 10 + ((x2 >> 1) + 1)] = pk(v0, v1);
        }
    }
    __syncthreads();

    // ---- stage 3: conv3(16->32) via dot2 + relu + spatial mean ----
    {
        const int wv = __builtin_amdgcn_readfirstlane(t >> 6);
        const int ln = t & 63;
        const int x3 = ln & 7, y3 = ln >> 3;
        float a3[8];
        #pragma unroll
        for (int o = 0; o < 8; ++o) a3[o] = b3[wv * 8 + o];

        #pragma unroll
        for (int icp = 0; icp < 8; ++icp) {
            h2 pt[9];
            #pragma unroll
            for (int ky = 0; ky < 3; ++ky)
                #pragma unroll
                for (int kx = 0; kx < 3; ++kx)
                    pt[ky * 3 + kx] = p2h[icp * 100 + (y3 + ky) * 10 + (x3 + kx)];
            #pragma unroll
            for (int k = 0; k < 9; ++k)
                #pragma unroll
                for (int o = 0; o < 8; ++o)
                    a3[o] = __builtin_amdgcn_fdot2(pt[k],
                                w3p[((wv * 8 + icp) * 9 + k) * 8 + o], a3[o], false);
        }
        #pragma unroll
        for (int o = 0; o < 8; ++o) {
            float v = fmaxf(a3[o], 0.f);
            #pragma unroll
            for (int off = 32; off; off >>= 1) v += __shfl_xor(v, off);
            if (ln == 0) fs[wv * 8 + o] = v * (1.f / 64.f);
        }
    }
    __syncthreads();

    // ---- stage 4: MLP head ----
    if (t < 32) {
        float s = 0.f;
        #pragma unroll
        for (int j = 0; j < 32; ++j) s = fmaf(gw1[t * 32 + j], fs[j], s);
        as[t] = fast_tanh(s);
    }
    __syncthreads();
    if (t < 16) {
        float s = 0.f;
        #pragma unroll
        for (int j = 0; j < 32; ++j) s = fmaf(gw2[t * 32 + j], as[j], s);
        gs[t] = fast_tanh(s);
    }
    __syncthreads();
    if (t < 16) {
        const int r = t >> 2, c = t & 3;
        float qv = 0.f, kv = 0.f;
        #pragma unroll
        for (int j = 0; j < 4; ++j) {
            qv = fmaf(gs[r * 4 + j], rot[j * 4 + c], qv);
            kv = fmaf(gs[r * 4 + j], rot[c * 4 + j], kv);
        }
        g_out[b * 16 + t] = gs[t];
        q_out[b * 16 + t] = qv;
        k_out[b * 16 + t] = kv;
    }
}

// ---------------------------------------------------------------------------
// Kernel 2: attention, 4 rows/block, q forced into SGPRs (block-uniform).
// ---------------------------------------------------------------------------
__global__ __launch_bounds__(256) void k_attn(
    const float* __restrict__ qg, const float* __restrict__ kg,
    const float* __restrict__ gg, const float* __restrict__ ent,
    const float* __restrict__ rw, const float* __restrict__ rb,
    const float* __restrict__ cw, const float* __restrict__ cb,
    float* __restrict__ outp, int B)
{
    __shared__ float red[4][4][20];

    const int t = threadIdx.x;
    const int lane = t & 63;
    const int w = t >> 6;
    const int r0 = blockIdx.x * 4;

    const float temp = (cosf(ent[0]) + cosf(ent[1]) + cosf(ent[2])) * (1.f / 3.f);
    const float scale = uniform_f(temp * 0.25f);

    float q[4][16];
    #pragma unroll
    for (int r = 0; r < 4; ++r)
        #pragma unroll
        for (int j = 0; j < 16; ++j)
            q[r][j] = uniform_f(qg[(r0 + r) * 16 + j]) * scale;

    float m[4], l[4], acc[4][16];
    #pragma unroll
    for (int r = 0; r < 4; ++r) {
        m[r] = -1e30f; l[r] = 0.f;
        #pragma unroll
        for (int j = 0; j < 16; ++j) acc[r][j] = 0.f;
    }

    const int iters = B >> 8;
    for (int i = 0; i < iters; ++i) {
        const int col = i * 256 + w * 64 + lane;

        const float4* kp = (const float4*)(kg + (size_t)col * 16);
        const float4 ka = kp[0], kb = kp[1], kc = kp[2], kd = kp[3];
        const float kv[16] = {ka.x, ka.y, ka.z, ka.w, kb.x, kb.y, kb.z, kb.w,
                              kc.x, kc.y, kc.z, kc.w, kd.x, kd.y, kd.z, kd.w};

        float s[4];
        #pragma unroll
        for (int r = 0; r < 4; ++r) {
            float sv = q[r][0] * kv[0];
            #pragma unroll
            for (int j = 1; j < 16; ++j) sv = fmaf(q[r][j], kv[j], sv);
            s[r] = sv;
        }

        float mn[4];
        bool ch = false;
        #pragma unroll
        for (int r = 0; r < 4; ++r) {
            mn[r] = fmaxf(m[r], s[r]);
            ch = ch | (mn[r] > m[r]);
        }
        if (__ballot(ch)) {
            #pragma unroll
            for (int r = 0; r < 4; ++r) {
                const float corr = exp2f((m[r] - mn[r]) * LOG2E);
                l[r] *= corr;
                #pragma unroll
                for (int j = 0; j < 16; ++j) acc[r][j] *= corr;
                m[r] = mn[r];
            }
        }

        float e[4];
        #pragma unroll
        for (int r = 0; r < 4; ++r) {
            e[r] = exp2f((s[r] - m[r]) * LOG2E);
            l[r] += e[r];
        }

        const float4* gp = (const float4*)(gg + (size_t)col * 16);
        const float4 ga = gp[0], gb = gp[1], gc = gp[2], gd = gp[3];
        const float gv[16] = {ga.x, ga.y, ga.z, ga.w, gb.x, gb.y, gb.z, gb.w,
                              gc.x, gc.y, gc.z, gc.w, gd.x, gd.y, gd.z, gd.w};
        #pragma unroll
        for (int r = 0; r < 4; ++r)
            #pragma unroll
            for (int j = 0; j < 16; ++j)
                acc[r][j] = fmaf(e[r], gv[j], acc[r][j]);
    }

    #pragma unroll
    for (int r = 0; r < 4; ++r) {
        const float mo = m[r];
        float mm = mo;
        #pragma unroll
        for (int off = 1; off < 64; off <<= 1) mm = fmaxf(mm, __shfl_xor(mm, off));
        const float f = exp2f((mo - mm) * LOG2E);
        m[r] = mm;
        l[r] *= f;
        #pragma unroll
        for (int j = 0; j < 16; ++j) acc[r][j] *= f;
        #pragma unroll
        for (int off = 1; off < 64; off <<= 1) {
            l[r] += __shfl_xor(l[r], off);
            #pragma unroll
            for (int j = 0; j < 16; ++j) acc[r][j] += __shfl_xor(acc[r][j], off);
        }
    }

    if (lane == 0) {
        #pragma unroll
        for (int r = 0; r < 4; ++r) {
            red[w][r][0] = m[r];
            red[w][r][1] = l[r];
            #pragma unroll
            for (int j = 0; j < 16; ++j) red[w][r][4 + j] = acc[r][j];
        }
    }
    __syncthreads();

    if (t < 4) {
        const int r = t;
        const int row = r0 + r;
        float M = red[0][r][0];
        for (int ww = 1; ww < 4; ++ww) M = fmaxf(M, red[ww][r][0]);
        float L = 0.f, A[16];
        #pragma unroll
        for (int j = 0; j < 16; ++j) A[j] = 0.f;
        for (int ww = 0; ww < 4; ++ww) {
            const float c = exp2f((red[ww][r][0] - M) * LOG2E);
            L = fmaf(red[ww][r][1], c, L);
            #pragma unroll
            for (int j = 0; j < 16; ++j) A[j] = fmaf(red[ww][r][4 + j], c, A[j]);
        }
        const float il = 1.f / L;

        float redv[2];
        #pragma unroll
        for (int c = 0; c < 2; ++c) {
            float sv = rb[c];
            #pragma unroll
            for (int j = 0; j < 16; ++j) sv = fmaf(gg[row * 16 + j], rw[c * 32 + j], sv);
            #pragma unroll
            for (int j = 0; j < 16; ++j) sv = fmaf(A[j] * il, rw[c * 32 + 16 + j], sv);
            redv[c] = sv;
        }
        outp[row * 2 + 0] = cb[0] + cw[0] * redv[0] + cw[1] * redv[1];
        outp[row * 2 + 1] = cb[1] + cw[2] * redv[0] + cw[3] * redv[1];
    }
}

// ---------------------------------------------------------------------------
// Kernel 3: BatchNorm1d(2), batch stats, in-place on d_out.
// ---------------------------------------------------------------------------
__global__ __launch_bounds__(1024) void k_bn(
    float* __restrict__ data, const float* __restrict__ gamma,
    const float* __restrict__ beta, int B)
{
    __shared__ float red[16][4];
    __shared__ float coef[4];
    const int t = threadIdx.x;
    float s0 = 0.f, s1 = 0.f, q0 = 0.f, q1 = 0.f;
    for (int i = t; i < B; i += 1024) {
        const float2 v = ((const float2*)data)[i];
        s0 += v.x; q0 += v.x * v.x;
        s1 += v.y; q1 += v.y * v.y;
    }
    #pragma unroll
    for (int off = 32; off; off >>= 1) {
        s0 += __shfl_xor(s0, off); q0 += __shfl_xor(q0, off);
        s1 += __shfl_xor(s1, off); q1 += __shfl_xor(q1, off);
    }
    if ((t & 63) == 0) {
        red[t >> 6][0] = s0; red[t >> 6][1] = q0;
        red[t >> 6][2] = s1; red[t >> 6][3] = q1;
    }
    __syncthreads();
    if (t == 0) {
        float S0 = 0.f, Q0 = 0.f, S1 = 0.f, Q1 = 0.f;
        for (int w = 0; w < 16; ++w) {
            S0 += red[w][0]; Q0 += red[w][1]; S1 += red[w][2]; Q1 += red[w][3];
        }
        const float inv = 1.f / (float)B;
        const float mu0 = S0 * inv, mu1 = S1 * inv;
        const float v0 = Q0 * inv - mu0 * mu0;
        const float v1 = Q1 * inv - mu1 * mu1;
        const float sc0 = gamma[0] * rsqrtf(v0 + 1e-5f);
        const float sc1 = gamma[1] * rsqrtf(v1 + 1e-5f);
        coef[0] = sc0; coef[1] = beta[0] - mu0 * sc0;
        coef[2] = sc1; coef[3] = beta[1] - mu1 * sc1;
    }
    __syncthreads();
    const float sc0 = coef[0], sh0 = coef[1], sc1 = coef[2], sh1 = coef[3];
    for (int i = t; i < B; i += 1024) {
        float2 v = ((const float2*)data)[i];
        v.x = fmaf(v.x, sc0, sh0);
        v.y = fmaf(v.y, sc1, sh1);
        ((float2*)data)[i] = v;
    }
}

extern "C" void kernel_launch(void* const* d_in, const int* in_sizes, int n_in,
                              void* d_out, int out_size, void* d_ws, size_t ws_size,
                              hipStream_t stream)
{
    (void)n_in; (void)out_size; (void)ws_size;
    const float* x   = (const float*)d_in[0];
    const float* w1  = (const float*)d_in[1];
    const float* b1  = (const float*)d_in[2];
    const float* w2  = (const float*)d_in[3];
    const float* b2  = (const float*)d_in[4];
    const float* w3  = (const float*)d_in[5];
    const float* b3  = (const float*)d_in[6];
    const float* gw1 = (const float*)d_in[7];
    const float* gw2 = (const float*)d_in[8];
    const float* rot = (const float*)d_in[9];
    const float* ent = (const float*)d_in[10];
    const float* rw  = (const float*)d_in[11];
    const float* rbv = (const float*)d_in[12];
    const float* cw  = (const float*)d_in[13];
    const float* cbv = (const float*)d_in[14];
    const float* gam = (const float*)d_in[15];
    const float* bet = (const float*)d_in[16];

    const int B = in_sizes[0] / (32 * 32);   // 4096

    float* ws    = (float*)d_ws;
    float* g_buf = ws;
    float* q_buf = ws + (size_t)B * 16;
    float* k_buf = ws + (size_t)B * 32;
    h2*    w2p   = (h2*)(ws + (size_t)B * 48);         // 576 half2
    h2*    w3p   = w2p + 576;                          // 2304 half2
    float* pre   = (float*)d_out;

    k_pack<<<1, 256, 0, stream>>>(w2, w3, w2p, w3p);
    k_cnn<<<B, 256, 0, stream>>>(x, w1, b1, w2p, b2, w3p, b3, gw1, gw2, rot,
                                 g_buf, q_buf, k_buf);
    k_attn<<<B / 4, 256, 0, stream>>>(q_buf, k_buf, g_buf, ent, rw, rbv, cw, cbv,
                                      pre, B);
    k_bn<<<1, 1024, 0, stream>>>(pre, gam, bet, B);
}

// Round 5
// 174.521 us; speedup vs baseline: 2.4236x; 1.8012x over previous
//
#include <hip/hip_runtime.h>
#include <math.h>

#define LOG2E 1.4426950408889634f

typedef _Float16 h2v __attribute__((ext_vector_type(2)));
typedef _Float16 h4  __attribute__((ext_vector_type(4)));
typedef _Float16 h8  __attribute__((ext_vector_type(8)));
typedef float    f4  __attribute__((ext_vector_type(4)));

__device__ __forceinline__ h2v pk(float a, float b) {
    return __builtin_bit_cast(h2v, __builtin_amdgcn_cvt_pkrtz(a, b));
}

__device__ __forceinline__ f4 mfma16(h8 a, h8 b, f4 c) {
    return __builtin_amdgcn_mfma_f32_16x16x32_f16(a, b, c, 0, 0, 0);
}

__device__ __forceinline__ float fast_tanh(float x) {
    const float xc = fminf(fmaxf(x, -15.f), 15.f);
    const float t = exp2f(xc * (2.f * LOG2E));
    return (t - 1.f) * __builtin_amdgcn_rcpf(t + 1.f);
}

__device__ __forceinline__ float uniform_f(float x) {
    return __int_as_float(__builtin_amdgcn_readfirstlane(__float_as_int(x)));
}

// ---------------------------------------------------------------------------
// Prelude: pack conv2/conv3 weights into MFMA A-fragment order (fp16).
//  w2f[((c*64)+lane)*8+j]          : A[oc=lane&15][k=c*32+(lane>>4)*8+j]
//     k decodes as shift s=c*4+(lane>>4), ic=j; zero for s>=9.
//  w3f[(((mt*5)+c)*64+lane)*8+j]   : A[oc=mt*16+(lane&15)][k=c*32+(lane>>4)*8+j]
//     kk=(lane>>4)*8+j: ic=kk&15, shift=c*2+(kk>>4); zero for shift>=9.
// ---------------------------------------------------------------------------
__global__ __launch_bounds__(256) void k_pack(
    const float* __restrict__ w2, const float* __restrict__ w3,
    _Float16* __restrict__ w2f, _Float16* __restrict__ w3f)
{
    for (int idx = threadIdx.x; idx < 1536; idx += 256) {
        const int j = idx & 7;
        const int lane = (idx >> 3) & 63;
        const int c = idx >> 9;
        const int oc = lane & 15;
        const int s = c * 4 + (lane >> 4);
        w3f[0] = w3f[0];  // no-op to keep compiler honest about aliasing
        w2f[idx] = (s < 9) ? (_Float16)w2[oc * 72 + j * 9 + s] : (_Float16)0.f;
    }
    for (int idx = threadIdx.x; idx < 5120; idx += 256) {
        const int j = idx & 7;
        const int lane = (idx >> 3) & 63;
        const int rest = idx >> 9;          // mt*5 + c
        const int mt = rest / 5;
        const int oc = mt * 16 + (lane & 15);
        const int kk = (lane >> 4) * 8 + j;
        const int ic = kk & 15;
        const int sh = (rest - mt * 5) * 2 + (kk >> 4);
        w3f[idx] = (sh < 9) ? (_Float16)w3[oc * 144 + ic * 9 + sh] : (_Float16)0.f;
    }
}

// ---------------------------------------------------------------------------
// Kernel 1 v4: per-image CNN. conv1 fp32 VALU; conv2/conv3 on MFMA
// (16x16x32 f16, fp32 accum) with chunked implicit-im2col in LDS.
// LDS regions: [0,16384) = xs (stage1) / B2 chunks (conv2) / B3 (conv3);
//              p1 cells [y][x][4 h2], p2 cells [y][x][8 h2] channel-interleaved.
// ---------------------------------------------------------------------------
__global__ __launch_bounds__(256) void k_cnn(
    const float* __restrict__ x,
    const float* __restrict__ w1, const float* __restrict__ b1,
    const _Float16* __restrict__ w2f, const float* __restrict__ b2,
    const _Float16* __restrict__ w3f, const float* __restrict__ b3,
    const float* __restrict__ gw1,
    const float* __restrict__ gw2,
    const float* __restrict__ rot,
    float* __restrict__ g_out, float* __restrict__ q_out, float* __restrict__ k_out)
{
    __shared__ __align__(16) char smem[16384 + 5184 + 3200 + 256 + 128 + 128 + 64];
    float* xs   = (float*)smem;                       // 34x34 fp32 (aliases B2/B3)
    h8*  B2h8   = (h8*)smem;                          // [4 kq][256 pos]
    h8*  B3h8   = (h8*)smem;                          // [4 kq][64 pos]
    h8*  p1c    = (h8*)(smem + 16384);                // [18][18] cells of 8 halves
    h8*  p2hc   = (h8*)(smem + 16384 + 5184);         // [10][10] cells, 2 h8 each
    h4*  p2h4   = (h4*)(smem + 16384 + 5184);         // same region, h4 view
    float* fsum = (float*)(smem + 16384 + 5184 + 3200);   // [2 mt][2 half][16]
    float* fs   = fsum + 64;
    float* as   = fs + 32;
    float* gs   = as + 32;

    const int t = threadIdx.x;
    const int b = blockIdx.x;
    const int lane = t & 63;
    const int w = __builtin_amdgcn_readfirstlane(t >> 6);
    const int nn = lane & 15;       // MFMA col / A-B row selector
    const int kq = lane >> 4;       // MFMA quad

    const h8 hzero = (h8)(_Float16)0.f;
    const f4 fzero = {0.f, 0.f, 0.f, 0.f};

    // zero xs + p1/p2 halos
    for (int i = t; i < 1156; i += 256) xs[i] = 0.f;
    {
        unsigned* z1 = (unsigned*)p1c;
        for (int i = t; i < 1296; i += 256) z1[i] = 0u;
        unsigned* z2 = (unsigned*)p2hc;
        for (int i = t; i < 800; i += 256) z2[i] = 0u;
    }
    __syncthreads();

    // load image interior
    {
        const float4 v = ((const float4*)(x + (size_t)b * 1024))[t];
        const int row = t >> 3;
        const int col = (t & 7) << 2;
        float* dst = &xs[(row + 1) * 34 + col + 1];
        dst[0] = v.x; dst[1] = v.y; dst[2] = v.z; dst[3] = v.w;
    }
    __syncthreads();

    // ---- stage 1: conv1(1->8) fp32 + relu + maxpool2 -> p1 cells ----
    {
        const int px = t & 15, py = t >> 4;
        float pa[4][4];
        #pragma unroll
        for (int iy = 0; iy < 4; ++iy)
            #pragma unroll
            for (int ix = 0; ix < 4; ++ix)
                pa[iy][ix] = xs[(2 * py + iy) * 34 + (2 * px + ix)];

        float r[8];
        #pragma unroll
        for (int oc = 0; oc < 8; ++oc) {
            float mx = -1e30f;
            #pragma unroll
            for (int sy = 0; sy < 2; ++sy)
                #pragma unroll
                for (int sx = 0; sx < 2; ++sx) {
                    float s = b1[oc];
                    #pragma unroll
                    for (int ky = 0; ky < 3; ++ky)
                        #pragma unroll
                        for (int kx = 0; kx < 3; ++kx)
                            s = fmaf(pa[sy + ky][sx + kx], w1[oc * 9 + ky * 3 + kx], s);
                    mx = fmaxf(mx, s);
                }
            r[oc] = fmaxf(mx, 0.f);
        }
        union { h8 v; h2v p[4]; } u;
        #pragma unroll
        for (int ocp = 0; ocp < 4; ++ocp) u.p[ocp] = pk(r[2 * ocp], r[2 * ocp + 1]);
        // NOTE: stage1 reads xs which aliases B2 — this write goes to p1 (separate);
        // the barrier inside the c-loop below protects xs death vs B2 birth.
        p1c[(py + 1) * 18 + (px + 1)] = u.v;
    }

    // A-fragments for conv2 (same for every wave)
    h8 a2[3];
    #pragma unroll
    for (int c = 0; c < 3; ++c) a2[c] = ((const h8*)w2f)[c * 64 + lane];

    // ---- conv2(8->16) as GEMM [16][96]x[96][256], 3 K-chunks ----
    f4 accp[4] = {fzero, fzero, fzero, fzero};
    {
        const int y2 = t >> 4, x2 = t & 15;
        #pragma unroll
        for (int c = 0; c < 3; ++c) {
            __syncthreads();   // previous chunk's frag reads done (c=0: stage1 done)
            #pragma unroll
            for (int sl = 0; sl < 4; ++sl) {
                const int s = c * 4 + sl;
                h8 v = hzero;
                if (s < 9) {
                    const int ky = s / 3, kx = s % 3;
                    v = p1c[(y2 + ky) * 18 + (x2 + kx)];
                }
                B2h8[sl * 256 + t] = v;
            }
            __syncthreads();
            #pragma unroll
            for (int p = 0; p < 4; ++p) {
                const h8 bf = B2h8[kq * 256 + (4 * w + p) * 16 + nn];
                accp[p] = mfma16(a2[c], bf, accp[p]);
            }
        }
    }

    // ---- conv2 epilogue: +bias, relu, 2x2 maxpool -> p2 cells ----
    {
        float bq[4];
        #pragma unroll
        for (int r = 0; r < 4; ++r) bq[r] = b2[kq * 4 + r];
        #pragma unroll
        for (int i = 0; i < 2; ++i) {        // y-pairs (4w+2i, 4w+2i+1)
            float m2[4];
            #pragma unroll
            for (int r = 0; r < 4; ++r) {
                const float v0 = fmaxf(accp[2 * i][r] + bq[r], 0.f);
                const float v1 = fmaxf(accp[2 * i + 1][r] + bq[r], 0.f);
                float mv = fmaxf(v0, v1);
                mv = fmaxf(mv, __shfl_xor(mv, 1));   // x-pair (col n vs n^1)
                m2[r] = mv;
            }
            if ((lane & 1) == 0) {
                const int px = nn >> 1;
                const int py = 2 * w + i;
                union { h4 v; h2v p[2]; } u;
                u.p[0] = pk(m2[0], m2[1]);
                u.p[1] = pk(m2[2], m2[3]);
                p2h4[((py + 1) * 10 + (px + 1)) * 4 + kq] = u.v;
            }
        }
    }

    // A-fragments for conv3 (per m-tile of this wave)
    const int mt = w >> 1;
    const int nt0 = (w & 1) * 2;
    h8 a3[5];
    #pragma unroll
    for (int c = 0; c < 5; ++c) a3[c] = ((const h8*)w3f)[(mt * 5 + c) * 64 + lane];

    // ---- conv3(16->32) as GEMM [32][160]x[160][64], 5 K-chunks ----
    f4 acc3[2] = {fzero, fzero};
    {
        const int pos = t & 63;
        const int yy = pos >> 3, xx = pos & 7;
        #pragma unroll
        for (int c = 0; c < 5; ++c) {
            __syncthreads();   // protects p2 writes (c=0) and B3 reuse (c>0)
            {
                const int sh = 2 * c + (w >> 1 & 1 ? 0 : 0, (t >> 6) >> 1);  // placeholder
                (void)sh;
            }
            {
                const int kq3 = t >> 6;
                const int shv = 2 * c + (kq3 >> 1);
                h8 v = hzero;
                if (shv < 9) {
                    const int ky = (shv * 11) >> 5;   // /3 for 0..8
                    const int kx = shv - 3 * ky;
                    v = p2hc[((yy + ky) * 10 + (xx + kx)) * 2 + (kq3 & 1)];
                }
                B3h8[kq3 * 64 + pos] = v;
            }
            __syncthreads();
            #pragma unroll
            for (int p = 0; p < 2; ++p) {
                const h8 bf = B3h8[kq * 64 + (nt0 + p) * 16 + nn];
                acc3[p] = mfma16(a3[c], bf, acc3[p]);
            }
        }
    }

    // ---- conv3 epilogue: +bias, relu, spatial sum -> fsum ----
    {
        float bq[4];
        #pragma unroll
        for (int r = 0; r < 4; ++r) bq[r] = b3[mt * 16 + kq * 4 + r];
        float sv[4];
        #pragma unroll
        for (int r = 0; r < 4; ++r) {
            float s = fmaxf(acc3[0][r] + bq[r], 0.f) + fmaxf(acc3[1][r] + bq[r], 0.f);
            #pragma unroll
            for (int off = 1; off < 16; off <<= 1) s += __shfl_xor(s, off);
            sv[r] = s;
        }
        if (nn == 0) {
            const f4 pack = {sv[0], sv[1], sv[2], sv[3]};
            ((f4*)fsum)[mt * 8 + (w & 1) * 4 + kq] = pack;
        }
    }
    __syncthreads();

    // ---- stage 4: mean + MLP head ----
    if (t < 32)
        fs[t] = (fsum[(t >> 4) * 32 + (t & 15)] +
                 fsum[(t >> 4) * 32 + 16 + (t & 15)]) * (1.f / 64.f);
    __syncthreads();
    if (t < 32) {
        float s = 0.f;
        #pragma unroll
        for (int j = 0; j < 32; ++j) s = fmaf(gw1[t * 32 + j], fs[j], s);
        as[t] = fast_tanh(s);
    }
    __syncthreads();
    if (t < 16) {
        float s = 0.f;
        #pragma unroll
        for (int j = 0; j < 32; ++j) s = fmaf(gw2[t * 32 + j], as[j], s);
        gs[t] = fast_tanh(s);
    }
    __syncthreads();
    if (t < 16) {
        const int r = t >> 2, c = t & 3;
        float qv = 0.f, kv = 0.f;
        #pragma unroll
        for (int j = 0; j < 4; ++j) {
            qv = fmaf(gs[r * 4 + j], rot[j * 4 + c], qv);
            kv = fmaf(gs[r * 4 + j], rot[c * 4 + j], kv);
        }
        g_out[b * 16 + t] = gs[t];
        q_out[b * 16 + t] = qv;
        k_out[b * 16 + t] = kv;
    }
}

// ---------------------------------------------------------------------------
// Kernel 2: attention, 4 rows/block, q in SGPRs (unchanged from R4).
// ---------------------------------------------------------------------------
__global__ __launch_bounds__(256) void k_attn(
    const float* __restrict__ qg, const float* __restrict__ kg,
    const float* __restrict__ gg, const float* __restrict__ ent,
    const float* __restrict__ rw, const float* __restrict__ rb,
    const float* __restrict__ cw, const float* __restrict__ cb,
    float* __restrict__ outp, int B)
{
    __shared__ float red[4][4][20];

    const int t = threadIdx.x;
    const int lane = t & 63;
    const int w = t >> 6;
    const int r0 = blockIdx.x * 4;

    const float temp = (cosf(ent[0]) + cosf(ent[1]) + cosf(ent[2])) * (1.f / 3.f);
    const float scale = uniform_f(temp * 0.25f);

    float q[4][16];
    #pragma unroll
    for (int r = 0; r < 4; ++r)
        #pragma unroll
        for (int j = 0; j < 16; ++j)
            q[r][j] = uniform_f(qg[(r0 + r) * 16 + j]) * scale;

    float m[4], l[4], acc[4][16];
    #pragma unroll
    for (int r = 0; r < 4; ++r) {
        m[r] = -1e30f; l[r] = 0.f;
        #pragma unroll
        for (int j = 0; j < 16; ++j) acc[r][j] = 0.f;
    }

    const int iters = B >> 8;
    for (int i = 0; i < iters; ++i) {
        const int col = i * 256 + w * 64 + lane;

        const float4* kp = (const float4*)(kg + (size_t)col * 16);
        const float4 ka = kp[0], kb = kp[1], kc = kp[2], kd = kp[3];
        const float kv[16] = {ka.x, ka.y, ka.z, ka.w, kb.x, kb.y, kb.z, kb.w,
                              kc.x, kc.y, kc.z, kc.w, kd.x, kd.y, kd.z, kd.w};

        float s[4];
        #pragma unroll
        for (int r = 0; r < 4; ++r) {
            float sv = q[r][0] * kv[0];
            #pragma unroll
            for (int j = 1; j < 16; ++j) sv = fmaf(q[r][j], kv[j], sv);
            s[r] = sv;
        }

        float mn[4];
        bool ch = false;
        #pragma unroll
        for (int r = 0; r < 4; ++r) {
            mn[r] = fmaxf(m[r], s[r]);
            ch = ch | (mn[r] > m[r]);
        }
        if (__ballot(ch)) {
            #pragma unroll
            for (int r = 0; r < 4; ++r) {
                const float corr = exp2f((m[r] - mn[r]) * LOG2E);
                l[r] *= corr;
                #pragma unroll
                for (int j = 0; j < 16; ++j) acc[r][j] *= corr;
                m[r] = mn[r];
            }
        }

        float e[4];
        #pragma unroll
        for (int r = 0; r < 4; ++r) {
            e[r] = exp2f((s[r] - m[r]) * LOG2E);
            l[r] += e[r];
        }

        const float4* gp = (const float4*)(gg + (size_t)col * 16);
        const float4 ga = gp[0], gb = gp[1], gc = gp[2], gd = gp[3];
        const float gv[16] = {ga.x, ga.y, ga.z, ga.w, gb.x, gb.y, gb.z, gb.w,
                              gc.x, gc.y, gc.z, gc.w, gd.x, gd.y, gd.z, gd.w};
        #pragma unroll
        for (int r = 0; r < 4; ++r)
            #pragma unroll
            for (int j = 0; j < 16; ++j)
                acc[r][j] = fmaf(e[r], gv[j], acc[r][j]);
    }

    #pragma unroll
    for (int r = 0; r < 4; ++r) {
        const float mo = m[r];
        float mm = mo;
        #pragma unroll
        for (int off = 1; off < 64; off <<= 1) mm = fmaxf(mm, __shfl_xor(mm, off));
        const float f = exp2f((mo - mm) * LOG2E);
        m[r] = mm;
        l[r] *= f;
        #pragma unroll
        for (int j = 0; j < 16; ++j) acc[r][j] *= f;
        #pragma unroll
        for (int off = 1; off < 64; off <<= 1) {
            l[r] += __shfl_xor(l[r], off);
            #pragma unroll
            for (int j = 0; j < 16; ++j) acc[r][j] += __shfl_xor(acc[r][j], off);
        }
    }

    if (lane == 0) {
        #pragma unroll
        for (int r = 0; r < 4; ++r) {
            red[w][r][0] = m[r];
            red[w][r][1] = l[r];
            #pragma unroll
            for (int j = 0; j < 16; ++j) red[w][r][4 + j] = acc[r][j];
        }
    }
    __syncthreads();

    if (t < 4) {
        const int r = t;
        const int row = r0 + r;
        float M = red[0][r][0];
        for (int ww = 1; ww < 4; ++ww) M = fmaxf(M, red[ww][r][0]);
        float L = 0.f, A[16];
        #pragma unroll
        for (int j = 0; j < 16; ++j) A[j] = 0.f;
        for (int ww = 0; ww < 4; ++ww) {
            const float c = exp2f((red[ww][r][0] - M) * LOG2E);
            L = fmaf(red[ww][r][1], c, L);
            #pragma unroll
            for (int j = 0; j < 16; ++j) A[j] = fmaf(red[ww][r][4 + j], c, A[j]);
        }
        const float il = 1.f / L;

        float redv[2];
        #pragma unroll
        for (int c = 0; c < 2; ++c) {
            float sv = rb[c];
            #pragma unroll
            for (int j = 0; j < 16; ++j) sv = fmaf(gg[row * 16 + j], rw[c * 32 + j], sv);
            #pragma unroll
            for (int j = 0; j < 16; ++j) sv = fmaf(A[j] * il, rw[c * 32 + 16 + j], sv);
            redv[c] = sv;
        }
        outp[row * 2 + 0] = cb[0] + cw[0] * redv[0] + cw[1] * redv[1];
        outp[row * 2 + 1] = cb[1] + cw[2] * redv[0] + cw[3] * redv[1];
    }
}

// ---------------------------------------------------------------------------
// Kernel 3: BatchNorm1d(2), batch stats, in-place on d_out.
// ---------------------------------------------------------------------------
__global__ __launch_bounds__(1024) void k_bn(
    float* __restrict__ data, const float* __restrict__ gamma,
    const float* __restrict__ beta, int B)
{
    __shared__ float red[16][4];
    __shared__ float coef[4];
    const int t = threadIdx.x;
    float s0 = 0.f, s1 = 0.f, q0 = 0.f, q1 = 0.f;
    for (int i = t; i < B; i += 1024) {
        const float2 v = ((const float2*)data)[i];
        s0 += v.x; q0 += v.x * v.x;
        s1 += v.y; q1 += v.y * v.y;
    }
    #pragma unroll
    for (int off = 32; off; off >>= 1) {
        s0 += __shfl_xor(s0, off); q0 += __shfl_xor(q0, off);
        s1 += __shfl_xor(s1, off); q1 += __shfl_xor(q1, off);
    }
    if ((t & 63) == 0) {
        red[t >> 6][0] = s0; red[t >> 6][1] = q0;
        red[t >> 6][2] = s1; red[t >> 6][3] = q1;
    }
    __syncthreads();
    if (t == 0) {
        float S0 = 0.f, Q0 = 0.f, S1 = 0.f, Q1 = 0.f;
        for (int w = 0; w < 16; ++w) {
            S0 += red[w][0]; Q0 += red[w][1]; S1 += red[w][2]; Q1 += red[w][3];
        }
        const float inv = 1.f / (float)B;
        const float mu0 = S0 * inv, mu1 = S1 * inv;
        const float v0 = Q0 * inv - mu0 * mu0;
        const float v1 = Q1 * inv - mu1 * mu1;
        const float sc0 = gamma[0] * rsqrtf(v0 + 1e-5f);
        const float sc1 = gamma[1] * rsqrtf(v1 + 1e-5f);
        coef[0] = sc0; coef[1] = beta[0] - mu0 * sc0;
        coef[2] = sc1; coef[3] = beta[1] - mu1 * sc1;
    }
    __syncthreads();
    const float sc0 = coef[0], sh0 = coef[1], sc1 = coef[2], sh1 = coef[3];
    for (int i = t; i < B; i += 1024) {
        float2 v = ((const float2*)data)[i];
        v.x = fmaf(v.x, sc0, sh0);
        v.y = fmaf(v.y, sc1, sh1);
        ((float2*)data)[i] = v;
    }
}

extern "C" void kernel_launch(void* const* d_in, const int* in_sizes, int n_in,
                              void* d_out, int out_size, void* d_ws, size_t ws_size,
                              hipStream_t stream)
{
    (void)n_in; (void)out_size; (void)ws_size;
    const float* x   = (const float*)d_in[0];
    const float* w1  = (const float*)d_in[1];
    const float* b1  = (const float*)d_in[2];
    const float* w2  = (const float*)d_in[3];
    const float* b2  = (const float*)d_in[4];
    const float* w3  = (const float*)d_in[5];
    const float* b3  = (const float*)d_in[6];
    const float* gw1 = (const float*)d_in[7];
    const float* gw2 = (const float*)d_in[8];
    const float* rot = (const float*)d_in[9];
    const float* ent = (const float*)d_in[10];
    const float* rw  = (const float*)d_in[11];
    const float* rbv = (const float*)d_in[12];
    const float* cw  = (const float*)d_in[13];
    const float* cbv = (const float*)d_in[14];
    const float* gam = (const float*)d_in[15];
    const float* bet = (const float*)d_in[16];

    const int B = in_sizes[0] / (32 * 32);   // 4096

    float* ws    = (float*)d_ws;
    float* g_buf = ws;
    float* q_buf = ws + (size_t)B * 16;
    float* k_buf = ws + (size_t)B * 32;
    _Float16* w2f = (_Float16*)(ws + (size_t)B * 48);   // 1536 halves (3072B)
    _Float16* w3f = w2f + 1536;                          // 5120 halves
    float* pre   = (float*)d_out;

    k_pack<<<1, 256, 0, stream>>>(w2, w3, w2f, w3f);
    k_cnn<<<B, 256, 0, stream>>>(x, w1, b1, w2f, b2, w3f, b3, gw1, gw2, rot,
                                 g_buf, q_buf, k_buf);
    k_attn<<<B / 4, 256, 0, stream>>>(q_buf, k_buf, g_buf, ent, rw, rbv, cw, cbv,
                                      pre, B);
    k_bn<<<1, 1024, 0, stream>>>(pre, gam, bet, B);
}

// Round 6
// 172.508 us; speedup vs baseline: 2.4519x; 1.0117x over previous
//
#include <hip/hip_runtime.h>
#include <math.h>

#define LOG2E 1.4426950408889634f

typedef _Float16 h2v __attribute__((ext_vector_type(2)));
typedef _Float16 h4  __attribute__((ext_vector_type(4)));
typedef _Float16 h8  __attribute__((ext_vector_type(8)));
typedef float    f4  __attribute__((ext_vector_type(4)));

__device__ __forceinline__ h2v pk(float a, float b) {
    return __builtin_bit_cast(h2v, __builtin_amdgcn_cvt_pkrtz(a, b));
}

__device__ __forceinline__ f4 mfma16(h8 a, h8 b, f4 c) {
    return __builtin_amdgcn_mfma_f32_16x16x32_f16(a, b, c, 0, 0, 0);
}

__device__ __forceinline__ float fast_tanh(float x) {
    const float xc = fminf(fmaxf(x, -15.f), 15.f);
    const float t = exp2f(xc * (2.f * LOG2E));
    return (t - 1.f) * __builtin_amdgcn_rcpf(t + 1.f);
}

__device__ __forceinline__ h2v uniform_h2(h2v v) {
    return __builtin_bit_cast(h2v,
        __builtin_amdgcn_readfirstlane(__builtin_bit_cast(int, v)));
}

// ---------------------------------------------------------------------------
// Prelude: pack conv2/conv3 weights into MFMA A-fragment order (fp16).
// ---------------------------------------------------------------------------
__global__ __launch_bounds__(256) void k_pack(
    const float* __restrict__ w2, const float* __restrict__ w3,
    _Float16* __restrict__ w2f, _Float16* __restrict__ w3f)
{
    for (int idx = threadIdx.x; idx < 1536; idx += 256) {
        const int j = idx & 7;
        const int lane = (idx >> 3) & 63;
        const int c = idx >> 9;
        const int oc = lane & 15;
        const int s = c * 4 + (lane >> 4);
        w2f[idx] = (s < 9) ? (_Float16)w2[oc * 72 + j * 9 + s] : (_Float16)0.f;
    }
    for (int idx = threadIdx.x; idx < 5120; idx += 256) {
        const int j = idx & 7;
        const int lane = (idx >> 3) & 63;
        const int rest = idx >> 9;          // mt*5 + c
        const int mt = rest / 5;
        const int oc = mt * 16 + (lane & 15);
        const int kk = (lane >> 4) * 8 + j;
        const int ic = kk & 15;
        const int sh = (rest - mt * 5) * 2 + (kk >> 4);
        w3f[idx] = (sh < 9) ? (_Float16)w3[oc * 144 + ic * 9 + sh] : (_Float16)0.f;
    }
}

// ---------------------------------------------------------------------------
// Kernel 1 v5: per-image CNN (conv2/conv3 on MFMA, unchanged from R5) +
// MLP head. Outputs now SoA fp16 pairs: gh/qh/kh[jp*B + b], scale folded
// into q (needs ent).
// ---------------------------------------------------------------------------
__global__ __launch_bounds__(256) void k_cnn(
    const float* __restrict__ x,
    const float* __restrict__ w1, const float* __restrict__ b1,
    const _Float16* __restrict__ w2f, const float* __restrict__ b2,
    const _Float16* __restrict__ w3f, const float* __restrict__ b3,
    const float* __restrict__ gw1,
    const float* __restrict__ gw2,
    const float* __restrict__ rot,
    const float* __restrict__ ent,
    h2v* __restrict__ gh, h2v* __restrict__ qh, h2v* __restrict__ kh, int Bc)
{
    __shared__ __align__(16) char smem[16384 + 5184 + 3200 + 576 + 128];
    float* xs   = (float*)smem;                       // 34x34 fp32 (aliases B2/B3)
    h8*  B2h8   = (h8*)smem;                          // [4 kq][256 pos]
    h8*  B3h8   = (h8*)smem;                          // [4 kq][64 pos]
    h8*  p1c    = (h8*)(smem + 16384);                // [18][18] cells of 8 halves
    h8*  p2hc   = (h8*)(smem + 16384 + 5184);         // [10][10] cells, 2 h8 each
    h4*  p2h4   = (h4*)(smem + 16384 + 5184);         // same region, h4 view
    float* fsum = (float*)(smem + 16384 + 5184 + 3200);   // [2 mt][2 half][16]
    float* fs   = fsum + 64;
    float* as   = fs + 32;
    float* gs   = as + 32;
    float* qs   = gs + 16;
    float* ks   = qs + 16;

    const int t = threadIdx.x;
    const int b = blockIdx.x;
    const int lane = t & 63;
    const int w = __builtin_amdgcn_readfirstlane(t >> 6);
    const int nn = lane & 15;
    const int kq = lane >> 4;

    const h8 hzero = (h8)(_Float16)0.f;
    const f4 fzero = {0.f, 0.f, 0.f, 0.f};

    for (int i = t; i < 1156; i += 256) xs[i] = 0.f;
    {
        unsigned* z1 = (unsigned*)p1c;
        for (int i = t; i < 1296; i += 256) z1[i] = 0u;
        unsigned* z2 = (unsigned*)p2hc;
        for (int i = t; i < 800; i += 256) z2[i] = 0u;
    }
    __syncthreads();

    {
        const float4 v = ((const float4*)(x + (size_t)b * 1024))[t];
        const int row = t >> 3;
        const int col = (t & 7) << 2;
        float* dst = &xs[(row + 1) * 34 + col + 1];
        dst[0] = v.x; dst[1] = v.y; dst[2] = v.z; dst[3] = v.w;
    }
    __syncthreads();

    // ---- stage 1: conv1(1->8) fp32 + relu + maxpool2 -> p1 cells ----
    {
        const int px = t & 15, py = t >> 4;
        float pa[4][4];
        #pragma unroll
        for (int iy = 0; iy < 4; ++iy)
            #pragma unroll
            for (int ix = 0; ix < 4; ++ix)
                pa[iy][ix] = xs[(2 * py + iy) * 34 + (2 * px + ix)];

        float r[8];
        #pragma unroll
        for (int oc = 0; oc < 8; ++oc) {
            float mx = -1e30f;
            #pragma unroll
            for (int sy = 0; sy < 2; ++sy)
                #pragma unroll
                for (int sx = 0; sx < 2; ++sx) {
                    float s = b1[oc];
                    #pragma unroll
                    for (int ky = 0; ky < 3; ++ky)
                        #pragma unroll
                        for (int kx = 0; kx < 3; ++kx)
                            s = fmaf(pa[sy + ky][sx + kx], w1[oc * 9 + ky * 3 + kx], s);
                    mx = fmaxf(mx, s);
                }
            r[oc] = fmaxf(mx, 0.f);
        }
        union { h8 v; h2v p[4]; } u;
        #pragma unroll
        for (int ocp = 0; ocp < 4; ++ocp) u.p[ocp] = pk(r[2 * ocp], r[2 * ocp + 1]);
        p1c[(py + 1) * 18 + (px + 1)] = u.v;
    }

    h8 a2[3];
    #pragma unroll
    for (int c = 0; c < 3; ++c) a2[c] = ((const h8*)w2f)[c * 64 + lane];

    // ---- conv2(8->16) as GEMM [16][96]x[96][256], 3 K-chunks ----
    f4 accp[4] = {fzero, fzero, fzero, fzero};
    {
        const int y2 = t >> 4, x2 = t & 15;
        #pragma unroll
        for (int c = 0; c < 3; ++c) {
            __syncthreads();
            #pragma unroll
            for (int sl = 0; sl < 4; ++sl) {
                const int s = c * 4 + sl;
                h8 v = hzero;
                if (s < 9) {
                    const int ky = s / 3, kx = s % 3;
                    v = p1c[(y2 + ky) * 18 + (x2 + kx)];
                }
                B2h8[sl * 256 + t] = v;
            }
            __syncthreads();
            #pragma unroll
            for (int p = 0; p < 4; ++p) {
                const h8 bf = B2h8[kq * 256 + (4 * w + p) * 16 + nn];
                accp[p] = mfma16(a2[c], bf, accp[p]);
            }
        }
    }

    // ---- conv2 epilogue: +bias, relu, 2x2 maxpool -> p2 cells ----
    {
        float bq[4];
        #pragma unroll
        for (int r = 0; r < 4; ++r) bq[r] = b2[kq * 4 + r];
        #pragma unroll
        for (int i = 0; i < 2; ++i) {
            float m2[4];
            #pragma unroll
            for (int r = 0; r < 4; ++r) {
                const float v0 = fmaxf(accp[2 * i][r] + bq[r], 0.f);
                const float v1 = fmaxf(accp[2 * i + 1][r] + bq[r], 0.f);
                float mv = fmaxf(v0, v1);
                mv = fmaxf(mv, __shfl_xor(mv, 1));
                m2[r] = mv;
            }
            if ((lane & 1) == 0) {
                const int px = nn >> 1;
                const int py = 2 * w + i;
                union { h4 v; h2v p[2]; } u;
                u.p[0] = pk(m2[0], m2[1]);
                u.p[1] = pk(m2[2], m2[3]);
                p2h4[((py + 1) * 10 + (px + 1)) * 4 + kq] = u.v;
            }
        }
    }

    const int mt = w >> 1;
    const int nt0 = (w & 1) * 2;
    h8 a3[5];
    #pragma unroll
    for (int c = 0; c < 5; ++c) a3[c] = ((const h8*)w3f)[(mt * 5 + c) * 64 + lane];

    // ---- conv3(16->32) as GEMM [32][160]x[160][64], 5 K-chunks ----
    f4 acc3[2] = {fzero, fzero};
    {
        const int pos = t & 63;
        const int yy = pos >> 3, xx = pos & 7;
        #pragma unroll
        for (int c = 0; c < 5; ++c) {
            __syncthreads();
            {
                const int kq3 = t >> 6;
                const int shv = 2 * c + (kq3 >> 1);
                h8 v = hzero;
                if (shv < 9) {
                    const int ky = (shv * 11) >> 5;
                    const int kx = shv - 3 * ky;
                    v = p2hc[((yy + ky) * 10 + (xx + kx)) * 2 + (kq3 & 1)];
                }
                B3h8[kq3 * 64 + pos] = v;
            }
            __syncthreads();
            #pragma unroll
            for (int p = 0; p < 2; ++p) {
                const h8 bf = B3h8[kq * 64 + (nt0 + p) * 16 + nn];
                acc3[p] = mfma16(a3[c], bf, acc3[p]);
            }
        }
    }

    // ---- conv3 epilogue: +bias, relu, spatial sum -> fsum ----
    {
        float bq[4];
        #pragma unroll
        for (int r = 0; r < 4; ++r) bq[r] = b3[mt * 16 + kq * 4 + r];
        float sv[4];
        #pragma unroll
        for (int r = 0; r < 4; ++r) {
            float s = fmaxf(acc3[0][r] + bq[r], 0.f) + fmaxf(acc3[1][r] + bq[r], 0.f);
            #pragma unroll
            for (int off = 1; off < 16; off <<= 1) s += __shfl_xor(s, off);
            sv[r] = s;
        }
        if (nn == 0) {
            const f4 pack = {sv[0], sv[1], sv[2], sv[3]};
            ((f4*)fsum)[mt * 8 + (w & 1) * 4 + kq] = pack;
        }
    }
    __syncthreads();

    // ---- stage 4: mean + MLP head ----
    if (t < 32)
        fs[t] = (fsum[(t >> 4) * 32 + (t & 15)] +
                 fsum[(t >> 4) * 32 + 16 + (t & 15)]) * (1.f / 64.f);
    __syncthreads();
    if (t < 32) {
        float s = 0.f;
        #pragma unroll
        for (int j = 0; j < 32; ++j) s = fmaf(gw1[t * 32 + j], fs[j], s);
        as[t] = fast_tanh(s);
    }
    __syncthreads();
    if (t < 16) {
        float s = 0.f;
        #pragma unroll
        for (int j = 0; j < 32; ++j) s = fmaf(gw2[t * 32 + j], as[j], s);
        gs[t] = fast_tanh(s);
    }
    __syncthreads();
    if (t < 16) {
        const int r = t >> 2, c = t & 3;
        float qv = 0.f, kv = 0.f;
        #pragma unroll
        for (int j = 0; j < 4; ++j) {
            qv = fmaf(gs[r * 4 + j], rot[j * 4 + c], qv);
            kv = fmaf(gs[r * 4 + j], rot[c * 4 + j], kv);
        }
        qs[t] = qv;
        ks[t] = kv;
    }
    __syncthreads();
    if (t < 8) {
        const float temp = (cosf(ent[0]) + cosf(ent[1]) + cosf(ent[2])) * (1.f / 3.f);
        const float scale = temp * 0.25f;   // temp / sqrt(16)
        gh[t * Bc + b] = pk(gs[2 * t], gs[2 * t + 1]);
        qh[t * Bc + b] = pk(qs[2 * t] * scale, qs[2 * t + 1] * scale);
        kh[t * Bc + b] = pk(ks[2 * t], ks[2 * t + 1]);
    }
}

// ---------------------------------------------------------------------------
// Kernel 2 v3: attention over SoA fp16-pair q/k/g. Coalesced dword loads
// (4 cache lines per instr vs 64 with the old AoS layout), fdot2 scores.
// ---------------------------------------------------------------------------
__global__ __launch_bounds__(256) void k_attn(
    const h2v* __restrict__ qh, const h2v* __restrict__ kh,
    const h2v* __restrict__ gh,
    const float* __restrict__ rw, const float* __restrict__ rb,
    const float* __restrict__ cw, const float* __restrict__ cb,
    float* __restrict__ outp, int B)
{
    __shared__ float red[4][4][20];

    const int t = threadIdx.x;
    const int lane = t & 63;
    const int w = t >> 6;
    const int r0 = blockIdx.x * 4;

    // q rows (scale pre-folded in k_cnn), block-uniform -> SGPRs
    h2v q[4][8];
    #pragma unroll
    for (int r = 0; r < 4; ++r)
        #pragma unroll
        for (int jp = 0; jp < 8; ++jp)
            q[r][jp] = uniform_h2(qh[jp * B + (r0 + r)]);

    float m[4], l[4], acc[4][16];
    #pragma unroll
    for (int r = 0; r < 4; ++r) {
        m[r] = -1e30f; l[r] = 0.f;
        #pragma unroll
        for (int j = 0; j < 16; ++j) acc[r][j] = 0.f;
    }

    const int iters = B >> 8;
    for (int i = 0; i < iters; ++i) {
        const int col = i * 256 + w * 64 + lane;

        h2v kv[8];
        #pragma unroll
        for (int jp = 0; jp < 8; ++jp) kv[jp] = kh[jp * B + col];

        float s[4];
        #pragma unroll
        for (int r = 0; r < 4; ++r) {
            float sv = 0.f;
            #pragma unroll
            for (int jp = 0; jp < 8; ++jp)
                sv = __builtin_amdgcn_fdot2(q[r][jp], kv[jp], sv, false);
            s[r] = sv;
        }

        float mn[4];
        bool ch = false;
        #pragma unroll
        for (int r = 0; r < 4; ++r) {
            mn[r] = fmaxf(m[r], s[r]);
            ch = ch | (mn[r] > m[r]);
        }
        if (__ballot(ch)) {
            #pragma unroll
            for (int r = 0; r < 4; ++r) {
                const float corr = exp2f((m[r] - mn[r]) * LOG2E);
                l[r] *= corr;
                #pragma unroll
                for (int j = 0; j < 16; ++j) acc[r][j] *= corr;
                m[r] = mn[r];
            }
        }

        float e[4];
        #pragma unroll
        for (int r = 0; r < 4; ++r) {
            e[r] = exp2f((s[r] - m[r]) * LOG2E);
            l[r] += e[r];
        }

        h2v gv[8];
        #pragma unroll
        for (int jp = 0; jp < 8; ++jp) gv[jp] = gh[jp * B + col];
        float gf[16];
        #pragma unroll
        for (int jp = 0; jp < 8; ++jp) {
            gf[2 * jp]     = (float)gv[jp][0];
            gf[2 * jp + 1] = (float)gv[jp][1];
        }
        #pragma unroll
        for (int r = 0; r < 4; ++r)
            #pragma unroll
            for (int j = 0; j < 16; ++j)
                acc[r][j] = fmaf(e[r], gf[j], acc[r][j]);
    }

    // ---- merge 64 lanes within the wave ----
    #pragma unroll
    for (int r = 0; r < 4; ++r) {
        const float mo = m[r];
        float mm = mo;
        #pragma unroll
        for (int off = 1; off < 64; off <<= 1) mm = fmaxf(mm, __shfl_xor(mm, off));
        const float f = exp2f((mo - mm) * LOG2E);
        m[r] = mm;
        l[r] *= f;
        #pragma unroll
        for (int j = 0; j < 16; ++j) acc[r][j] *= f;
        #pragma unroll
        for (int off = 1; off < 64; off <<= 1) {
            l[r] += __shfl_xor(l[r], off);
            #pragma unroll
            for (int j = 0; j < 16; ++j) acc[r][j] += __shfl_xor(acc[r][j], off);
        }
    }

    if (lane == 0) {
        #pragma unroll
        for (int r = 0; r < 4; ++r) {
            red[w][r][0] = m[r];
            red[w][r][1] = l[r];
            #pragma unroll
            for (int j = 0; j < 16; ++j) red[w][r][4 + j] = acc[r][j];
        }
    }
    __syncthreads();

    // ---- cross-wave merge + fused reduce/cls epilogue ----
    if (t < 4) {
        const int r = t;
        const int row = r0 + r;
        float M = red[0][r][0];
        for (int ww = 1; ww < 4; ++ww) M = fmaxf(M, red[ww][r][0]);
        float L = 0.f, A[16];
        #pragma unroll
        for (int j = 0; j < 16; ++j) A[j] = 0.f;
        for (int ww = 0; ww < 4; ++ww) {
            const float c = exp2f((red[ww][r][0] - M) * LOG2E);
            L = fmaf(red[ww][r][1], c, L);
            #pragma unroll
            for (int j = 0; j < 16; ++j) A[j] = fmaf(red[ww][r][4 + j], c, A[j]);
        }
        const float il = 1.f / L;

        float grow[16];
        #pragma unroll
        for (int jp = 0; jp < 8; ++jp) {
            const h2v v = gh[jp * B + row];
            grow[2 * jp]     = (float)v[0];
            grow[2 * jp + 1] = (float)v[1];
        }

        float redv[2];
        #pragma unroll
        for (int c = 0; c < 2; ++c) {
            float sv = rb[c];
            #pragma unroll
            for (int j = 0; j < 16; ++j) sv = fmaf(grow[j], rw[c * 32 + j], sv);
            #pragma unroll
            for (int j = 0; j < 16; ++j) sv = fmaf(A[j] * il, rw[c * 32 + 16 + j], sv);
            redv[c] = sv;
        }
        // fraud layers (all-zero params) are identity; classifier:
        outp[row * 2 + 0] = cb[0] + cw[0] * redv[0] + cw[1] * redv[1];
        outp[row * 2 + 1] = cb[1] + cw[2] * redv[0] + cw[3] * redv[1];
    }
}

// ---------------------------------------------------------------------------
// Kernel 3: BatchNorm1d(2), batch stats, in-place on d_out.
// ---------------------------------------------------------------------------
__global__ __launch_bounds__(1024) void k_bn(
    float* __restrict__ data, const float* __restrict__ gamma,
    const float* __restrict__ beta, int B)
{
    __shared__ float red[16][4];
    __shared__ float coef[4];
    const int t = threadIdx.x;
    float s0 = 0.f, s1 = 0.f, q0 = 0.f, q1 = 0.f;
    for (int i = t; i < B; i += 1024) {
        const float2 v = ((const float2*)data)[i];
        s0 += v.x; q0 += v.x * v.x;
        s1 += v.y; q1 += v.y * v.y;
    }
    #pragma unroll
    for (int off = 32; off; off >>= 1) {
        s0 += __shfl_xor(s0, off); q0 += __shfl_xor(q0, off);
        s1 += __shfl_xor(s1, off); q1 += __shfl_xor(q1, off);
    }
    if ((t & 63) == 0) {
        red[t >> 6][0] = s0; red[t >> 6][1] = q0;
        red[t >> 6][2] = s1; red[t >> 6][3] = q1;
    }
    __syncthreads();
    if (t == 0) {
        float S0 = 0.f, Q0 = 0.f, S1 = 0.f, Q1 = 0.f;
        for (int w = 0; w < 16; ++w) {
            S0 += red[w][0]; Q0 += red[w][1]; S1 += red[w][2]; Q1 += red[w][3];
        }
        const float inv = 1.f / (float)B;
        const float mu0 = S0 * inv, mu1 = S1 * inv;
        const float v0 = Q0 * inv - mu0 * mu0;
        const float v1 = Q1 * inv - mu1 * mu1;
        const float sc0 = gamma[0] * rsqrtf(v0 + 1e-5f);
        const float sc1 = gamma[1] * rsqrtf(v1 + 1e-5f);
        coef[0] = sc0; coef[1] = beta[0] - mu0 * sc0;
        coef[2] = sc1; coef[3] = beta[1] - mu1 * sc1;
    }
    __syncthreads();
    const float sc0 = coef[0], sh0 = coef[1], sc1 = coef[2], sh1 = coef[3];
    for (int i = t; i < B; i += 1024) {
        float2 v = ((const float2*)data)[i];
        v.x = fmaf(v.x, sc0, sh0);
        v.y = fmaf(v.y, sc1, sh1);
        ((float2*)data)[i] = v;
    }
}

extern "C" void kernel_launch(void* const* d_in, const int* in_sizes, int n_in,
                              void* d_out, int out_size, void* d_ws, size_t ws_size,
                              hipStream_t stream)
{
    (void)n_in; (void)out_size; (void)ws_size;
    const float* x   = (const float*)d_in[0];
    const float* w1  = (const float*)d_in[1];
    const float* b1  = (const float*)d_in[2];
    const float* w2  = (const float*)d_in[3];
    const float* b2  = (const float*)d_in[4];
    const float* w3  = (const float*)d_in[5];
    const float* b3  = (const float*)d_in[6];
    const float* gw1 = (const float*)d_in[7];
    const float* gw2 = (const float*)d_in[8];
    const float* rot = (const float*)d_in[9];
    const float* ent = (const float*)d_in[10];
    const float* rw  = (const float*)d_in[11];
    const float* rbv = (const float*)d_in[12];
    const float* cw  = (const float*)d_in[13];
    const float* cbv = (const float*)d_in[14];
    const float* gam = (const float*)d_in[15];
    const float* bet = (const float*)d_in[16];

    const int B = in_sizes[0] / (32 * 32);   // 4096

    h2v* gh = (h2v*)d_ws;                    // [8][B] fp16 pairs
    h2v* qh = gh + (size_t)8 * B;
    h2v* kh = qh + (size_t)8 * B;
    _Float16* w2f = (_Float16*)(kh + (size_t)8 * B);   // 1536 halves
    _Float16* w3f = w2f + 1536;                         // 5120 halves
    float* pre = (float*)d_out;

    k_pack<<<1, 256, 0, stream>>>(w2, w3, w2f, w3f);
    k_cnn<<<B, 256, 0, stream>>>(x, w1, b1, w2f, b2, w3f, b3, gw1, gw2, rot, ent,
                                 gh, qh, kh, B);
    k_attn<<<B / 4, 256, 0, stream>>>(qh, kh, gh, rw, rbv, cw, cbv, pre, B);
    k_bn<<<1, 1024, 0, stream>>>(pre, gam, bet, B);
}

// Round 8
// 171.524 us; speedup vs baseline: 2.4659x; 1.0057x over previous
//
#include <hip/hip_runtime.h>
#include <math.h>

#define LOG2E 1.4426950408889634f

typedef _Float16 h2v __attribute__((ext_vector_type(2)));
typedef _Float16 h4  __attribute__((ext_vector_type(4)));
typedef _Float16 h8  __attribute__((ext_vector_type(8)));
typedef float    f4  __attribute__((ext_vector_type(4)));

__device__ __forceinline__ h2v pk(float a, float b) {
    return __builtin_bit_cast(h2v, __builtin_amdgcn_cvt_pkrtz(a, b));
}

__device__ __forceinline__ f4 mfma16x32(h8 a, h8 b, f4 c) {
    return __builtin_amdgcn_mfma_f32_16x16x32_f16(a, b, c, 0, 0, 0);
}

// Legacy (pre-gfx950) intrinsic name has NO underscore before f16.
__device__ __forceinline__ f4 mfma16x16(h4 a, h4 b, f4 c) {
    return __builtin_amdgcn_mfma_f32_16x16x16f16(a, b, c, 0, 0, 0);
}

__device__ __forceinline__ float fast_tanh(float x) {
    const float xc = fminf(fmaxf(x, -15.f), 15.f);
    const float t = exp2f(xc * (2.f * LOG2E));
    return (t - 1.f) * __builtin_amdgcn_rcpf(t + 1.f);
}

// ---------------------------------------------------------------------------
// Prelude: pack conv2/conv3 weights into MFMA A-fragment order (fp16).
// ---------------------------------------------------------------------------
__global__ __launch_bounds__(256) void k_pack(
    const float* __restrict__ w2, const float* __restrict__ w3,
    _Float16* __restrict__ w2f, _Float16* __restrict__ w3f)
{
    for (int idx = threadIdx.x; idx < 1536; idx += 256) {
        const int j = idx & 7;
        const int lane = (idx >> 3) & 63;
        const int c = idx >> 9;
        const int oc = lane & 15;
        const int s = c * 4 + (lane >> 4);
        w2f[idx] = (s < 9) ? (_Float16)w2[oc * 72 + j * 9 + s] : (_Float16)0.f;
    }
    for (int idx = threadIdx.x; idx < 5120; idx += 256) {
        const int j = idx & 7;
        const int lane = (idx >> 3) & 63;
        const int rest = idx >> 9;          // mt*5 + c
        const int mt = rest / 5;
        const int oc = mt * 16 + (lane & 15);
        const int kk = (lane >> 4) * 8 + j;
        const int ic = kk & 15;
        const int sh = (rest - mt * 5) * 2 + (kk >> 4);
        w3f[idx] = (sh < 9) ? (_Float16)w3[oc * 144 + ic * 9 + sh] : (_Float16)0.f;
    }
}

// ---------------------------------------------------------------------------
// Kernel 1 v6: per-image CNN (conv2/conv3 on MFMA) + MLP head.
// Outputs: q16/k16/g16 AoS fp16 [row][16] (scale folded into q16), and
// gswz = g in PV A-fragment order: gswz[tile=col>>4][lane=q*16+d][j],
// holding g[col=tile*16+q*4+j][d].
// ---------------------------------------------------------------------------
__global__ __launch_bounds__(256) void k_cnn(
    const float* __restrict__ x,
    const float* __restrict__ w1, const float* __restrict__ b1,
    const _Float16* __restrict__ w2f, const float* __restrict__ b2,
    const _Float16* __restrict__ w3f, const float* __restrict__ b3,
    const float* __restrict__ gw1,
    const float* __restrict__ gw2,
    const float* __restrict__ rot,
    const float* __restrict__ ent,
    _Float16* __restrict__ q16, _Float16* __restrict__ k16,
    _Float16* __restrict__ g16, _Float16* __restrict__ gswz)
{
    __shared__ __align__(16) char smem[16384 + 5184 + 3200 + 576 + 128];
    float* xs   = (float*)smem;
    h8*  B2h8   = (h8*)smem;
    h8*  B3h8   = (h8*)smem;
    h8*  p1c    = (h8*)(smem + 16384);
    h8*  p2hc   = (h8*)(smem + 16384 + 5184);
    h4*  p2h4   = (h4*)(smem + 16384 + 5184);
    float* fsum = (float*)(smem + 16384 + 5184 + 3200);
    float* fs   = fsum + 64;
    float* as   = fs + 32;
    float* gs   = as + 32;
    float* qs   = gs + 16;
    float* ks   = qs + 16;

    const int t = threadIdx.x;
    const int b = blockIdx.x;
    const int lane = t & 63;
    const int w = __builtin_amdgcn_readfirstlane(t >> 6);
    const int nn = lane & 15;
    const int kq = lane >> 4;

    const h8 hzero = (h8)(_Float16)0.f;
    const f4 fzero = {0.f, 0.f, 0.f, 0.f};

    for (int i = t; i < 1156; i += 256) xs[i] = 0.f;
    {
        unsigned* z1 = (unsigned*)p1c;
        for (int i = t; i < 1296; i += 256) z1[i] = 0u;
        unsigned* z2 = (unsigned*)p2hc;
        for (int i = t; i < 800; i += 256) z2[i] = 0u;
    }
    __syncthreads();

    {
        const float4 v = ((const float4*)(x + (size_t)b * 1024))[t];
        const int row = t >> 3;
        const int col = (t & 7) << 2;
        float* dst = &xs[(row + 1) * 34 + col + 1];
        dst[0] = v.x; dst[1] = v.y; dst[2] = v.z; dst[3] = v.w;
    }
    __syncthreads();

    // ---- stage 1: conv1(1->8) fp32 + relu + maxpool2 -> p1 cells ----
    {
        const int px = t & 15, py = t >> 4;
        float pa[4][4];
        #pragma unroll
        for (int iy = 0; iy < 4; ++iy)
            #pragma unroll
            for (int ix = 0; ix < 4; ++ix)
                pa[iy][ix] = xs[(2 * py + iy) * 34 + (2 * px + ix)];

        float r[8];
        #pragma unroll
        for (int oc = 0; oc < 8; ++oc) {
            float mx = -1e30f;
            #pragma unroll
            for (int sy = 0; sy < 2; ++sy)
                #pragma unroll
                for (int sx = 0; sx < 2; ++sx) {
                    float s = b1[oc];
                    #pragma unroll
                    for (int ky = 0; ky < 3; ++ky)
                        #pragma unroll
                        for (int kx = 0; kx < 3; ++kx)
                            s = fmaf(pa[sy + ky][sx + kx], w1[oc * 9 + ky * 3 + kx], s);
                    mx = fmaxf(mx, s);
                }
            r[oc] = fmaxf(mx, 0.f);
        }
        union { h8 v; h2v p[4]; } u;
        #pragma unroll
        for (int ocp = 0; ocp < 4; ++ocp) u.p[ocp] = pk(r[2 * ocp], r[2 * ocp + 1]);
        p1c[(py + 1) * 18 + (px + 1)] = u.v;
    }

    h8 a2[3];
    #pragma unroll
    for (int c = 0; c < 3; ++c) a2[c] = ((const h8*)w2f)[c * 64 + lane];

    // ---- conv2(8->16) as GEMM, 3 K-chunks ----
    f4 accp[4] = {fzero, fzero, fzero, fzero};
    {
        const int y2 = t >> 4, x2 = t & 15;
        #pragma unroll
        for (int c = 0; c < 3; ++c) {
            __syncthreads();
            #pragma unroll
            for (int sl = 0; sl < 4; ++sl) {
                const int s = c * 4 + sl;
                h8 v = hzero;
                if (s < 9) {
                    const int ky = s / 3, kx = s % 3;
                    v = p1c[(y2 + ky) * 18 + (x2 + kx)];
                }
                B2h8[sl * 256 + t] = v;
            }
            __syncthreads();
            #pragma unroll
            for (int p = 0; p < 4; ++p) {
                const h8 bf = B2h8[kq * 256 + (4 * w + p) * 16 + nn];
                accp[p] = mfma16x32(a2[c], bf, accp[p]);
            }
        }
    }

    // ---- conv2 epilogue ----
    {
        float bq[4];
        #pragma unroll
        for (int r = 0; r < 4; ++r) bq[r] = b2[kq * 4 + r];
        #pragma unroll
        for (int i = 0; i < 2; ++i) {
            float m2[4];
            #pragma unroll
            for (int r = 0; r < 4; ++r) {
                const float v0 = fmaxf(accp[2 * i][r] + bq[r], 0.f);
                const float v1 = fmaxf(accp[2 * i + 1][r] + bq[r], 0.f);
                float mv = fmaxf(v0, v1);
                mv = fmaxf(mv, __shfl_xor(mv, 1));
                m2[r] = mv;
            }
            if ((lane & 1) == 0) {
                const int px = nn >> 1;
                const int py = 2 * w + i;
                union { h4 v; h2v p[2]; } u;
                u.p[0] = pk(m2[0], m2[1]);
                u.p[1] = pk(m2[2], m2[3]);
                p2h4[((py + 1) * 10 + (px + 1)) * 4 + kq] = u.v;
            }
        }
    }

    const int mt = w >> 1;
    const int nt0 = (w & 1) * 2;
    h8 a3[5];
    #pragma unroll
    for (int c = 0; c < 5; ++c) a3[c] = ((const h8*)w3f)[(mt * 5 + c) * 64 + lane];

    // ---- conv3(16->32) as GEMM, 5 K-chunks ----
    f4 acc3[2] = {fzero, fzero};
    {
        const int pos = t & 63;
        const int yy = pos >> 3, xx = pos & 7;
        #pragma unroll
        for (int c = 0; c < 5; ++c) {
            __syncthreads();
            {
                const int kq3 = t >> 6;
                const int shv = 2 * c + (kq3 >> 1);
                h8 v = hzero;
                if (shv < 9) {
                    const int ky = (shv * 11) >> 5;
                    const int kx = shv - 3 * ky;
                    v = p2hc[((yy + ky) * 10 + (xx + kx)) * 2 + (kq3 & 1)];
                }
                B3h8[kq3 * 64 + pos] = v;
            }
            __syncthreads();
            #pragma unroll
            for (int p = 0; p < 2; ++p) {
                const h8 bf = B3h8[kq * 64 + (nt0 + p) * 16 + nn];
                acc3[p] = mfma16x32(a3[c], bf, acc3[p]);
            }
        }
    }

    // ---- conv3 epilogue: +bias, relu, spatial sum ----
    {
        float bq[4];
        #pragma unroll
        for (int r = 0; r < 4; ++r) bq[r] = b3[mt * 16 + kq * 4 + r];
        float sv[4];
        #pragma unroll
        for (int r = 0; r < 4; ++r) {
            float s = fmaxf(acc3[0][r] + bq[r], 0.f) + fmaxf(acc3[1][r] + bq[r], 0.f);
            #pragma unroll
            for (int off = 1; off < 16; off <<= 1) s += __shfl_xor(s, off);
            sv[r] = s;
        }
        if (nn == 0) {
            const f4 pack = {sv[0], sv[1], sv[2], sv[3]};
            ((f4*)fsum)[mt * 8 + (w & 1) * 4 + kq] = pack;
        }
    }
    __syncthreads();

    // ---- stage 4: mean + MLP head ----
    if (t < 32)
        fs[t] = (fsum[(t >> 4) * 32 + (t & 15)] +
                 fsum[(t >> 4) * 32 + 16 + (t & 15)]) * (1.f / 64.f);
    __syncthreads();
    if (t < 32) {
        float s = 0.f;
        #pragma unroll
        for (int j = 0; j < 32; ++j) s = fmaf(gw1[t * 32 + j], fs[j], s);
        as[t] = fast_tanh(s);
    }
    __syncthreads();
    if (t < 16) {
        float s = 0.f;
        #pragma unroll
        for (int j = 0; j < 32; ++j) s = fmaf(gw2[t * 32 + j], as[j], s);
        gs[t] = fast_tanh(s);
    }
    __syncthreads();
    if (t < 16) {
        const int r = t >> 2, c = t & 3;
        float qv = 0.f, kv = 0.f;
        #pragma unroll
        for (int j = 0; j < 4; ++j) {
            qv = fmaf(gs[r * 4 + j], rot[j * 4 + c], qv);
            kv = fmaf(gs[r * 4 + j], rot[c * 4 + j], kv);
        }
        qs[t] = qv;
        ks[t] = kv;
    }
    __syncthreads();
    if (t < 8) {
        const float temp = (cosf(ent[0]) + cosf(ent[1]) + cosf(ent[2])) * (1.f / 3.f);
        const float scale = temp * 0.25f;   // temp / sqrt(16)
        ((h2v*)q16)[b * 8 + t] = pk(qs[2 * t] * scale, qs[2 * t + 1] * scale);
        ((h2v*)k16)[b * 8 + t] = pk(ks[2 * t], ks[2 * t + 1]);
        ((h2v*)g16)[b * 8 + t] = pk(gs[2 * t], gs[2 * t + 1]);
    }
    if (t < 16) {
        const int tile = b >> 4, lc = b & 15;
        gswz[tile * 256 + (((lc >> 2) * 16) + t) * 4 + (lc & 3)] = (_Float16)gs[t];
    }
}

// ---------------------------------------------------------------------------
// Kernel 2 v4: MFMA flash attention. Block = one 16-row Q-tile; 4 waves
// split 4096 cols. S^T = K·Q^T (mfma 16x16x16) leaves P in exactly the
// B-operand layout of O^T = V^T·P^T — no transpose between the two MFMAs.
// ---------------------------------------------------------------------------
__global__ __launch_bounds__(256) void k_attn(
    const _Float16* __restrict__ q16, const _Float16* __restrict__ k16,
    const _Float16* __restrict__ g16, const _Float16* __restrict__ gswz,
    const float* __restrict__ rw, const float* __restrict__ rb,
    const float* __restrict__ cw, const float* __restrict__ cb,
    float* __restrict__ outp, int B)
{
    __shared__ f4 lO[4][64];
    __shared__ float lm[4][16];
    __shared__ float ll[4][16];

    const int t = threadIdx.x;
    const int lane = t & 63;
    const int w = t >> 6;
    const int rt = blockIdx.x;          // row tile (16 rows)
    const int r = lane & 15;
    const int q = lane >> 4;
    const f4 fzero = {0.f, 0.f, 0.f, 0.f};

    // Q B-fragment: lane holds Q[rt*16+r][d=q*4+j] (scale pre-folded)
    const h4 qf = *(const h4*)(q16 + ((size_t)(rt * 16 + r)) * 16 + q * 4);

    float m = -1e30f, lp = 0.f;
    f4 O = fzero;

    const int strip = B >> 2;           // 1024 cols per wave
    const int cbeg = w * strip;
    for (int ci = 0; ci < strip; ci += 16) {
        const int c0 = cbeg + ci;
        // K A-fragment: lane holds K[c0+r][d=q*4+j]
        const h4 kf = *(const h4*)(k16 + ((size_t)(c0 + r)) * 16 + q * 4);
        // st[reg] = S[r][c0 + q*4 + reg]
        const f4 st = mfma16x16(kf, qf, fzero);

        float mx = fmaxf(fmaxf(st[0], st[1]), fmaxf(st[2], st[3]));
        mx = fmaxf(mx, __shfl_xor(mx, 16));
        mx = fmaxf(mx, __shfl_xor(mx, 32));
        if (__ballot(mx > m)) {
            const float mn = fmaxf(m, mx);
            const float a = exp2f((m - mn) * LOG2E);
            lp *= a;
            O[0] *= a; O[1] *= a; O[2] *= a; O[3] *= a;
            m = mn;
        }
        const float p0 = exp2f((st[0] - m) * LOG2E);
        const float p1 = exp2f((st[1] - m) * LOG2E);
        const float p2 = exp2f((st[2] - m) * LOG2E);
        const float p3 = exp2f((st[3] - m) * LOG2E);
        lp += (p0 + p1) + (p2 + p3);

        union { h4 v; h2v p[2]; } u;
        u.p[0] = pk(p0, p1);
        u.p[1] = pk(p2, p3);
        // V^T A-fragment: lane holds g[c0+q*4+j][d'=r] (pre-swizzled)
        const h4 gf = *(const h4*)(gswz + (size_t)((c0 >> 4)) * 256 + lane * 4);
        O = mfma16x16(gf, u.v, O);      // O[reg] = attn[r][d'=q*4+reg] (unnorm)
    }
    lp += __shfl_xor(lp, 16);
    lp += __shfl_xor(lp, 32);

    lO[w][lane] = O;
    if (lane < 16) { lm[w][lane] = m; ll[w][lane] = lp; }
    __syncthreads();

    if (w == 0) {
        float M = lm[0][r];
        #pragma unroll
        for (int ww = 1; ww < 4; ++ww) M = fmaxf(M, lm[ww][r]);
        float L = 0.f;
        f4 Om = fzero;
        #pragma unroll
        for (int ww = 0; ww < 4; ++ww) {
            const float f = exp2f((lm[ww][r] - M) * LOG2E);
            L = fmaf(ll[ww][r], f, L);
            const f4 ow = lO[ww][lane];
            Om[0] = fmaf(ow[0], f, Om[0]);
            Om[1] = fmaf(ow[1], f, Om[1]);
            Om[2] = fmaf(ow[2], f, Om[2]);
            Om[3] = fmaf(ow[3], f, Om[3]);
        }
        const float il = 1.f / L;
        // g row fragment: g[rt*16+r][d=q*4+j]
        const h4 gr = *(const h4*)(g16 + ((size_t)(rt * 16 + r)) * 16 + q * 4);

        float rv[2];
        #pragma unroll
        for (int c = 0; c < 2; ++c) {
            float s = 0.f;
            #pragma unroll
            for (int j = 0; j < 4; ++j) {
                s = fmaf((float)gr[j], rw[c * 32 + q * 4 + j], s);
                s = fmaf(Om[j] * il, rw[c * 32 + 16 + q * 4 + j], s);
            }
            s += __shfl_xor(s, 16);
            s += __shfl_xor(s, 32);
            rv[c] = s + rb[c];
        }
        if (q == 0) {
            // fraud layers (all-zero params) are identity; classifier:
            float2 o;
            o.x = cb[0] + cw[0] * rv[0] + cw[1] * rv[1];
            o.y = cb[1] + cw[2] * rv[0] + cw[3] * rv[1];
            ((float2*)outp)[rt * 16 + r] = o;
        }
    }
}

// ---------------------------------------------------------------------------
// Kernel 3: BatchNorm1d(2), batch stats, in-place on d_out.
// ---------------------------------------------------------------------------
__global__ __launch_bounds__(1024) void k_bn(
    float* __restrict__ data, const float* __restrict__ gamma,
    const float* __restrict__ beta, int B)
{
    __shared__ float red[16][4];
    __shared__ float coef[4];
    const int t = threadIdx.x;
    float s0 = 0.f, s1 = 0.f, q0 = 0.f, q1 = 0.f;
    for (int i = t; i < B; i += 1024) {
        const float2 v = ((const float2*)data)[i];
        s0 += v.x; q0 += v.x * v.x;
        s1 += v.y; q1 += v.y * v.y;
    }
    #pragma unroll
    for (int off = 32; off; off >>= 1) {
        s0 += __shfl_xor(s0, off); q0 += __shfl_xor(q0, off);
        s1 += __shfl_xor(s1, off); q1 += __shfl_xor(q1, off);
    }
    if ((t & 63) == 0) {
        red[t >> 6][0] = s0; red[t >> 6][1] = q0;
        red[t >> 6][2] = s1; red[t >> 6][3] = q1;
    }
    __syncthreads();
    if (t == 0) {
        float S0 = 0.f, Q0 = 0.f, S1 = 0.f, Q1 = 0.f;
        for (int w = 0; w < 16; ++w) {
            S0 += red[w][0]; Q0 += red[w][1]; S1 += red[w][2]; Q1 += red[w][3];
        }
        const float inv = 1.f / (float)B;
        const float mu0 = S0 * inv, mu1 = S1 * inv;
        const float v0 = Q0 * inv - mu0 * mu0;
        const float v1 = Q1 * inv - mu1 * mu1;
        const float sc0 = gamma[0] * rsqrtf(v0 + 1e-5f);
        const float sc1 = gamma[1] * rsqrtf(v1 + 1e-5f);
        coef[0] = sc0; coef[1] = beta[0] - mu0 * sc0;
        coef[2] = sc1; coef[3] = beta[1] - mu1 * sc1;
    }
    __syncthreads();
    const float sc0 = coef[0], sh0 = coef[1], sc1 = coef[2], sh1 = coef[3];
    for (int i = t; i < B; i += 1024) {
        float2 v = ((const float2*)data)[i];
        v.x = fmaf(v.x, sc0, sh0);
        v.y = fmaf(v.y, sc1, sh1);
        ((float2*)data)[i] = v;
    }
}

extern "C" void kernel_launch(void* const* d_in, const int* in_sizes, int n_in,
                              void* d_out, int out_size, void* d_ws, size_t ws_size,
                              hipStream_t stream)
{
    (void)n_in; (void)out_size; (void)ws_size;
    const float* x   = (const float*)d_in[0];
    const float* w1  = (const float*)d_in[1];
    const float* b1  = (const float*)d_in[2];
    const float* w2  = (const float*)d_in[3];
    const float* b2  = (const float*)d_in[4];
    const float* w3  = (const float*)d_in[5];
    const float* b3  = (const float*)d_in[6];
    const float* gw1 = (const float*)d_in[7];
    const float* gw2 = (const float*)d_in[8];
    const float* rot = (const float*)d_in[9];
    const float* ent = (const float*)d_in[10];
    const float* rw  = (const float*)d_in[11];
    const float* rbv = (const float*)d_in[12];
    const float* cw  = (const float*)d_in[13];
    const float* cbv = (const float*)d_in[14];
    const float* gam = (const float*)d_in[15];
    const float* bet = (const float*)d_in[16];

    const int B = in_sizes[0] / (32 * 32);   // 4096

    _Float16* q16  = (_Float16*)d_ws;                 // [B][16]
    _Float16* k16  = q16 + (size_t)B * 16;            // [B][16]
    _Float16* g16  = k16 + (size_t)B * 16;            // [B][16]
    _Float16* gswz = g16 + (size_t)B * 16;            // [B/16][64][4]
    _Float16* w2f  = gswz + (size_t)B * 16;           // 1536
    _Float16* w3f  = w2f + 1536;                      // 5120
    float* pre = (float*)d_out;

    k_pack<<<1, 256, 0, stream>>>(w2, w3, w2f, w3f);
    k_cnn<<<B, 256, 0, stream>>>(x, w1, b1, w2f, b2, w3f, b3, gw1, gw2, rot, ent,
                                 q16, k16, g16, gswz);
    k_attn<<<B / 16, 256, 0, stream>>>(q16, k16, g16, gswz, rw, rbv, cw, cbv,
                                       pre, B);
    k_bn<<<1, 1024, 0, stream>>>(pre, gam, bet, B);
}

// Round 9
// 169.665 us; speedup vs baseline: 2.4930x; 1.0110x over previous
//
#include <hip/hip_runtime.h>
#include <math.h>

#define LOG2E 1.4426950408889634f

typedef _Float16 h2v __attribute__((ext_vector_type(2)));
typedef _Float16 h4  __attribute__((ext_vector_type(4)));
typedef _Float16 h8  __attribute__((ext_vector_type(8)));
typedef float    f4  __attribute__((ext_vector_type(4)));

__device__ __forceinline__ h2v pk(float a, float b) {
    return __builtin_bit_cast(h2v, __builtin_amdgcn_cvt_pkrtz(a, b));
}

__device__ __forceinline__ f4 mfma16x32(h8 a, h8 b, f4 c) {
    return __builtin_amdgcn_mfma_f32_16x16x32_f16(a, b, c, 0, 0, 0);
}

// Legacy (pre-gfx950) intrinsic name has NO underscore before f16.
__device__ __forceinline__ f4 mfma16x16(h4 a, h4 b, f4 c) {
    return __builtin_amdgcn_mfma_f32_16x16x16f16(a, b, c, 0, 0, 0);
}

__device__ __forceinline__ float fast_tanh(float x) {
    const float xc = fminf(fmaxf(x, -15.f), 15.f);
    const float t = exp2f(xc * (2.f * LOG2E));
    return (t - 1.f) * __builtin_amdgcn_rcpf(t + 1.f);
}

// ---------------------------------------------------------------------------
// Prelude: pack conv weights. w2f/w3f in MFMA A-fragment order (fp16);
// w1 as (col0,col1) h2 pairs + fp32 col2 for the conv1 dot2 path.
// ---------------------------------------------------------------------------
__global__ __launch_bounds__(256) void k_pack(
    const float* __restrict__ w1,
    const float* __restrict__ w2, const float* __restrict__ w3,
    _Float16* __restrict__ w2f, _Float16* __restrict__ w3f,
    h2v* __restrict__ w1p, float* __restrict__ w1t)
{
    if (threadIdx.x < 24) {
        const int oc = threadIdx.x / 3, ky = threadIdx.x % 3;
        w1p[threadIdx.x] = pk(w1[oc * 9 + ky * 3 + 0], w1[oc * 9 + ky * 3 + 1]);
        w1t[threadIdx.x] = w1[oc * 9 + ky * 3 + 2];
    }
    for (int idx = threadIdx.x; idx < 1536; idx += 256) {
        const int j = idx & 7;
        const int lane = (idx >> 3) & 63;
        const int c = idx >> 9;
        const int oc = lane & 15;
        const int s = c * 4 + (lane >> 4);
        w2f[idx] = (s < 9) ? (_Float16)w2[oc * 72 + j * 9 + s] : (_Float16)0.f;
    }
    for (int idx = threadIdx.x; idx < 5120; idx += 256) {
        const int j = idx & 7;
        const int lane = (idx >> 3) & 63;
        const int rest = idx >> 9;          // mt*5 + c
        const int mt = rest / 5;
        const int oc = mt * 16 + (lane & 15);
        const int kk = (lane >> 4) * 8 + j;
        const int ic = kk & 15;
        const int sh = (rest - mt * 5) * 2 + (kk >> 4);
        w3f[idx] = (sh < 9) ? (_Float16)w3[oc * 144 + ic * 9 + sh] : (_Float16)0.f;
    }
}

// ---------------------------------------------------------------------------
// Kernel 1 v7: per-image CNN. conv1 via fdot2 (fp32 accum); conv2 MFMA with
// chunked staging; conv3 MFMA with SINGLE-SHOT staging (barriers 10 -> 2);
// halo-only LDS zeroing. Outputs q16/k16/g16 AoS fp16 + gswz (PV A-layout).
// ---------------------------------------------------------------------------
__global__ __launch_bounds__(256) void k_cnn(
    const float* __restrict__ x,
    const h2v* __restrict__ w1p, const float* __restrict__ w1t,
    const float* __restrict__ b1,
    const _Float16* __restrict__ w2f, const float* __restrict__ b2,
    const _Float16* __restrict__ w3f, const float* __restrict__ b3,
    const float* __restrict__ gw1,
    const float* __restrict__ gw2,
    const float* __restrict__ rot,
    const float* __restrict__ ent,
    _Float16* __restrict__ q16, _Float16* __restrict__ k16,
    _Float16* __restrict__ g16, _Float16* __restrict__ gswz)
{
    __shared__ __align__(16) char smem[16384 + 5184 + 3200 + 576 + 128];
    float* xs   = (float*)smem;                       // 34x34 fp32
    h8*  B2h8   = (h8*)smem;                          // conv2 staging (aliases xs)
    h8*  B3full = (h8*)smem;                          // conv3 full B [20][64] (aliases xs+p1c)
    h8*  p1c    = (h8*)(smem + 16384);                // [18][18] cells of 8 halves
    h8*  p2hc   = (h8*)(smem + 16384 + 5184);         // [10][10] cells, 2 h8 each
    h4*  p2h4   = (h4*)(smem + 16384 + 5184);
    float* fsum = (float*)(smem + 16384 + 5184 + 3200);
    float* fs   = fsum + 64;
    float* as   = fs + 32;
    float* gs   = as + 32;
    float* qs   = gs + 16;
    float* ks   = qs + 16;

    const int t = threadIdx.x;
    const int b = blockIdx.x;
    const int lane = t & 63;
    const int w = __builtin_amdgcn_readfirstlane(t >> 6);
    const int nn = lane & 15;
    const int kq = lane >> 4;

    const h8 hzero = (h8)(_Float16)0.f;
    const f4 fzero = {0.f, 0.f, 0.f, 0.f};

    // ---- halo-only zeroing (interiors are fully overwritten) ----
    if (t < 132) {               // xs border of 34x34
        int r, c;
        if (t < 34)       { r = 0;  c = t; }
        else if (t < 68)  { r = 33; c = t - 34; }
        else if (t < 100) { r = t - 68 + 1;  c = 0; }
        else              { r = t - 100 + 1; c = 33; }
        xs[r * 34 + c] = 0.f;
    } else if (t < 200) {        // p1c border of 18x18
        const int u = t - 132;
        int r, c;
        if (u < 18)      { r = 0;  c = u; }
        else if (u < 36) { r = 17; c = u - 18; }
        else if (u < 52) { r = u - 36 + 1; c = 0; }
        else             { r = u - 52 + 1; c = 17; }
        p1c[r * 18 + c] = hzero;
    } else if (t < 236) {        // p2hc border of 10x10 (2 h8 per cell)
        const int u = t - 200;
        int r, c;
        if (u < 10)      { r = 0; c = u; }
        else if (u < 20) { r = 9; c = u - 10; }
        else if (u < 28) { r = u - 20 + 1; c = 0; }
        else             { r = u - 28 + 1; c = 9; }
        p2hc[(r * 10 + c) * 2 + 0] = hzero;
        p2hc[(r * 10 + c) * 2 + 1] = hzero;
    }
    // image interior (disjoint from xs halo -> same barrier)
    {
        const float4 v = ((const float4*)(x + (size_t)b * 1024))[t];
        const int row = t >> 3;
        const int col = (t & 7) << 2;
        float* dst = &xs[(row + 1) * 34 + col + 1];
        dst[0] = v.x; dst[1] = v.y; dst[2] = v.z; dst[3] = v.w;
    }
    __syncthreads();

    // ---- stage 1: conv1(1->8) via fdot2 + relu + maxpool2 -> p1 cells ----
    {
        const int px = t & 15, py = t >> 4;
        float pa[4][4];
        #pragma unroll
        for (int iy = 0; iy < 4; ++iy)
            #pragma unroll
            for (int ix = 0; ix < 4; ++ix)
                pa[iy][ix] = xs[(2 * py + iy) * 34 + (2 * px + ix)];
        h2v pA[4], pB[4];
        #pragma unroll
        for (int r = 0; r < 4; ++r) {
            pA[r] = pk(pa[r][0], pa[r][1]);
            pB[r] = pk(pa[r][1], pa[r][2]);
        }

        float r8[8];
        #pragma unroll
        for (int oc = 0; oc < 8; ++oc) {
            const h2v wp0 = w1p[oc * 3 + 0], wp1 = w1p[oc * 3 + 1], wp2 = w1p[oc * 3 + 2];
            const float wt0 = w1t[oc * 3 + 0], wt1 = w1t[oc * 3 + 1], wt2 = w1t[oc * 3 + 2];
            const float bb = b1[oc];
            float mx = -1e30f;
            #pragma unroll
            for (int sy = 0; sy < 2; ++sy) {
                float s0 = bb, s1 = bb;
                s0 = __builtin_amdgcn_fdot2(pA[sy],     wp0, s0, false);
                s0 = __builtin_amdgcn_fdot2(pA[sy + 1], wp1, s0, false);
                s0 = __builtin_amdgcn_fdot2(pA[sy + 2], wp2, s0, false);
                s0 = fmaf(pa[sy][2], wt0, s0);
                s0 = fmaf(pa[sy + 1][2], wt1, s0);
                s0 = fmaf(pa[sy + 2][2], wt2, s0);
                s1 = __builtin_amdgcn_fdot2(pB[sy],     wp0, s1, false);
                s1 = __builtin_amdgcn_fdot2(pB[sy + 1], wp1, s1, false);
                s1 = __builtin_amdgcn_fdot2(pB[sy + 2], wp2, s1, false);
                s1 = fmaf(pa[sy][3], wt0, s1);
                s1 = fmaf(pa[sy + 1][3], wt1, s1);
                s1 = fmaf(pa[sy + 2][3], wt2, s1);
                mx = fmaxf(mx, fmaxf(s0, s1));
            }
            r8[oc] = fmaxf(mx, 0.f);
        }
        union { h8 v; h2v p[4]; } u;
        #pragma unroll
        for (int ocp = 0; ocp < 4; ++ocp) u.p[ocp] = pk(r8[2 * ocp], r8[2 * ocp + 1]);
        p1c[(py + 1) * 18 + (px + 1)] = u.v;
    }

    h8 a2[3];
    #pragma unroll
    for (int c = 0; c < 3; ++c) a2[c] = ((const h8*)w2f)[c * 64 + lane];

    // ---- conv2(8->16) as GEMM, 3 K-chunks ----
    f4 accp[4] = {fzero, fzero, fzero, fzero};
    {
        const int y2 = t >> 4, x2 = t & 15;
        #pragma unroll
        for (int c = 0; c < 3; ++c) {
            __syncthreads();
            #pragma unroll
            for (int sl = 0; sl < 4; ++sl) {
                const int s = c * 4 + sl;
                h8 v = hzero;
                if (s < 9) {
                    const int ky = s / 3, kx = s % 3;
                    v = p1c[(y2 + ky) * 18 + (x2 + kx)];
                }
                B2h8[sl * 256 + t] = v;
            }
            __syncthreads();
            #pragma unroll
            for (int p = 0; p < 4; ++p) {
                const h8 bf = B2h8[kq * 256 + (4 * w + p) * 16 + nn];
                accp[p] = mfma16x32(a2[c], bf, accp[p]);
            }
        }
    }

    // ---- conv2 epilogue: +bias, relu, 2x2 maxpool -> p2 cells ----
    {
        float bq[4];
        #pragma unroll
        for (int r = 0; r < 4; ++r) bq[r] = b2[kq * 4 + r];
        #pragma unroll
        for (int i = 0; i < 2; ++i) {
            float m2[4];
            #pragma unroll
            for (int r = 0; r < 4; ++r) {
                const float v0 = fmaxf(accp[2 * i][r] + bq[r], 0.f);
                const float v1 = fmaxf(accp[2 * i + 1][r] + bq[r], 0.f);
                float mv = fmaxf(v0, v1);
                mv = fmaxf(mv, __shfl_xor(mv, 1));
                m2[r] = mv;
            }
            if ((lane & 1) == 0) {
                const int px = nn >> 1;
                const int py = 2 * w + i;
                union { h4 v; h2v p[2]; } u;
                u.p[0] = pk(m2[0], m2[1]);
                u.p[1] = pk(m2[2], m2[3]);
                p2h4[((py + 1) * 10 + (px + 1)) * 4 + kq] = u.v;
            }
        }
    }

    const int mt = w >> 1;
    const int nt0 = (w & 1) * 2;
    h8 a3[5];
    #pragma unroll
    for (int c = 0; c < 5; ++c) a3[c] = ((const h8*)w3f)[(mt * 5 + c) * 64 + lane];

    // ---- conv3(16->32): single-shot staging of full B [20 slots][64 pos],
    //      then barrier-free MFMA loop. B3full reuses xs+p1c (both dead).
    __syncthreads();   // p2hc ready; conv2's B2h8/p1c reads complete
    #pragma unroll
    for (int ss = 0; ss < 5; ++ss) {
        const int idx = ss * 256 + t;
        const int slot = idx >> 6;          // 0..19 = c*4 + kq
        const int pos = idx & 63;
        const int c = slot >> 2;
        const int kq3 = slot & 3;
        const int shv = 2 * c + (kq3 >> 1);
        const int hh = kq3 & 1;
        const int yy = pos >> 3, xx = pos & 7;
        h8 v = hzero;
        if (shv < 9) {
            const int ky = (shv * 11) >> 5;
            const int kx = shv - 3 * ky;
            v = p2hc[((yy + ky) * 10 + (xx + kx)) * 2 + hh];
        }
        B3full[slot * 64 + pos] = v;
    }
    __syncthreads();

    f4 acc3[2] = {fzero, fzero};
    #pragma unroll
    for (int c = 0; c < 5; ++c) {
        #pragma unroll
        for (int p = 0; p < 2; ++p) {
            const h8 bf = B3full[(c * 4 + kq) * 64 + (nt0 + p) * 16 + nn];
            acc3[p] = mfma16x32(a3[c], bf, acc3[p]);
        }
    }

    // ---- conv3 epilogue: +bias, relu, spatial sum ----
    {
        float bq[4];
        #pragma unroll
        for (int r = 0; r < 4; ++r) bq[r] = b3[mt * 16 + kq * 4 + r];
        float sv[4];
        #pragma unroll
        for (int r = 0; r < 4; ++r) {
            float s = fmaxf(acc3[0][r] + bq[r], 0.f) + fmaxf(acc3[1][r] + bq[r], 0.f);
            #pragma unroll
            for (int off = 1; off < 16; off <<= 1) s += __shfl_xor(s, off);
            sv[r] = s;
        }
        if (nn == 0) {
            const f4 pack = {sv[0], sv[1], sv[2], sv[3]};
            ((f4*)fsum)[mt * 8 + (w & 1) * 4 + kq] = pack;
        }
    }
    __syncthreads();

    // ---- stage 4: mean + MLP head ----
    if (t < 32)
        fs[t] = (fsum[(t >> 4) * 32 + (t & 15)] +
                 fsum[(t >> 4) * 32 + 16 + (t & 15)]) * (1.f / 64.f);
    __syncthreads();
    if (t < 32) {
        float s = 0.f;
        #pragma unroll
        for (int j = 0; j < 32; ++j) s = fmaf(gw1[t * 32 + j], fs[j], s);
        as[t] = fast_tanh(s);
    }
    __syncthreads();
    if (t < 16) {
        float s = 0.f;
        #pragma unroll
        for (int j = 0; j < 32; ++j) s = fmaf(gw2[t * 32 + j], as[j], s);
        gs[t] = fast_tanh(s);
    }
    __syncthreads();
    if (t < 16) {
        const int r = t >> 2, c = t & 3;
        float qv = 0.f, kv = 0.f;
        #pragma unroll
        for (int j = 0; j < 4; ++j) {
            qv = fmaf(gs[r * 4 + j], rot[j * 4 + c], qv);
            kv = fmaf(gs[r * 4 + j], rot[c * 4 + j], kv);
        }
        qs[t] = qv;
        ks[t] = kv;
    }
    __syncthreads();
    if (t < 8) {
        const float temp = (cosf(ent[0]) + cosf(ent[1]) + cosf(ent[2])) * (1.f / 3.f);
        const float scale = temp * 0.25f;   // temp / sqrt(16)
        ((h2v*)q16)[b * 8 + t] = pk(qs[2 * t] * scale, qs[2 * t + 1] * scale);
        ((h2v*)k16)[b * 8 + t] = pk(ks[2 * t], ks[2 * t + 1]);
        ((h2v*)g16)[b * 8 + t] = pk(gs[2 * t], gs[2 * t + 1]);
    }
    if (t < 16) {
        const int tile = b >> 4, lc = b & 15;
        gswz[tile * 256 + (((lc >> 2) * 16) + t) * 4 + (lc & 3)] = (_Float16)gs[t];
    }
}

// ---------------------------------------------------------------------------
// Kernel 2 v4: MFMA flash attention (unchanged from R8).
// ---------------------------------------------------------------------------
__global__ __launch_bounds__(256) void k_attn(
    const _Float16* __restrict__ q16, const _Float16* __restrict__ k16,
    const _Float16* __restrict__ g16, const _Float16* __restrict__ gswz,
    const float* __restrict__ rw, const float* __restrict__ rb,
    const float* __restrict__ cw, const float* __restrict__ cb,
    float* __restrict__ outp, int B)
{
    __shared__ f4 lO[4][64];
    __shared__ float lm[4][16];
    __shared__ float ll[4][16];

    const int t = threadIdx.x;
    const int lane = t & 63;
    const int w = t >> 6;
    const int rt = blockIdx.x;
    const int r = lane & 15;
    const int q = lane >> 4;
    const f4 fzero = {0.f, 0.f, 0.f, 0.f};

    const h4 qf = *(const h4*)(q16 + ((size_t)(rt * 16 + r)) * 16 + q * 4);

    float m = -1e30f, lp = 0.f;
    f4 O = fzero;

    const int strip = B >> 2;
    const int cbeg = w * strip;
    for (int ci = 0; ci < strip; ci += 16) {
        const int c0 = cbeg + ci;
        const h4 kf = *(const h4*)(k16 + ((size_t)(c0 + r)) * 16 + q * 4);
        const f4 st = mfma16x16(kf, qf, fzero);

        float mx = fmaxf(fmaxf(st[0], st[1]), fmaxf(st[2], st[3]));
        mx = fmaxf(mx, __shfl_xor(mx, 16));
        mx = fmaxf(mx, __shfl_xor(mx, 32));
        if (__ballot(mx > m)) {
            const float mn = fmaxf(m, mx);
            const float a = exp2f((m - mn) * LOG2E);
            lp *= a;
            O[0] *= a; O[1] *= a; O[2] *= a; O[3] *= a;
            m = mn;
        }
        const float p0 = exp2f((st[0] - m) * LOG2E);
        const float p1 = exp2f((st[1] - m) * LOG2E);
        const float p2 = exp2f((st[2] - m) * LOG2E);
        const float p3 = exp2f((st[3] - m) * LOG2E);
        lp += (p0 + p1) + (p2 + p3);

        union { h4 v; h2v p[2]; } u;
        u.p[0] = pk(p0, p1);
        u.p[1] = pk(p2, p3);
        const h4 gf = *(const h4*)(gswz + (size_t)((c0 >> 4)) * 256 + lane * 4);
        O = mfma16x16(gf, u.v, O);
    }
    lp += __shfl_xor(lp, 16);
    lp += __shfl_xor(lp, 32);

    lO[w][lane] = O;
    if (lane < 16) { lm[w][lane] = m; ll[w][lane] = lp; }
    __syncthreads();

    if (w == 0) {
        float M = lm[0][r];
        #pragma unroll
        for (int ww = 1; ww < 4; ++ww) M = fmaxf(M, lm[ww][r]);
        float L = 0.f;
        f4 Om = fzero;
        #pragma unroll
        for (int ww = 0; ww < 4; ++ww) {
            const float f = exp2f((lm[ww][r] - M) * LOG2E);
            L = fmaf(ll[ww][r], f, L);
            const f4 ow = lO[ww][lane];
            Om[0] = fmaf(ow[0], f, Om[0]);
            Om[1] = fmaf(ow[1], f, Om[1]);
            Om[2] = fmaf(ow[2], f, Om[2]);
            Om[3] = fmaf(ow[3], f, Om[3]);
        }
        const float il = 1.f / L;
        const h4 gr = *(const h4*)(g16 + ((size_t)(rt * 16 + r)) * 16 + q * 4);

        float rv[2];
        #pragma unroll
        for (int c = 0; c < 2; ++c) {
            float s = 0.f;
            #pragma unroll
            for (int j = 0; j < 4; ++j) {
                s = fmaf((float)gr[j], rw[c * 32 + q * 4 + j], s);
                s = fmaf(Om[j] * il, rw[c * 32 + 16 + q * 4 + j], s);
            }
            s += __shfl_xor(s, 16);
            s += __shfl_xor(s, 32);
            rv[c] = s + rb[c];
        }
        if (q == 0) {
            float2 o;
            o.x = cb[0] + cw[0] * rv[0] + cw[1] * rv[1];
            o.y = cb[1] + cw[2] * rv[0] + cw[3] * rv[1];
            ((float2*)outp)[rt * 16 + r] = o;
        }
    }
}

// ---------------------------------------------------------------------------
// Kernel 3: BatchNorm1d(2), batch stats, in-place on d_out.
// ---------------------------------------------------------------------------
__global__ __launch_bounds__(1024) void k_bn(
    float* __restrict__ data, const float* __restrict__ gamma,
    const float* __restrict__ beta, int B)
{
    __shared__ float red[16][4];
    __shared__ float coef[4];
    const int t = threadIdx.x;
    float s0 = 0.f, s1 = 0.f, q0 = 0.f, q1 = 0.f;
    for (int i = t; i < B; i += 1024) {
        const float2 v = ((const float2*)data)[i];
        s0 += v.x; q0 += v.x * v.x;
        s1 += v.y; q1 += v.y * v.y;
    }
    #pragma unroll
    for (int off = 32; off; off >>= 1) {
        s0 += __shfl_xor(s0, off); q0 += __shfl_xor(q0, off);
        s1 += __shfl_xor(s1, off); q1 += __shfl_xor(q1, off);
    }
    if ((t & 63) == 0) {
        red[t >> 6][0] = s0; red[t >> 6][1] = q0;
        red[t >> 6][2] = s1; red[t >> 6][3] = q1;
    }
    __syncthreads();
    if (t == 0) {
        float S0 = 0.f, Q0 = 0.f, S1 = 0.f, Q1 = 0.f;
        for (int w = 0; w < 16; ++w) {
            S0 += red[w][0]; Q0 += red[w][1]; S1 += red[w][2]; Q1 += red[w][3];
        }
        const float inv = 1.f / (float)B;
        const float mu0 = S0 * inv, mu1 = S1 * inv;
        const float v0 = Q0 * inv - mu0 * mu0;
        const float v1 = Q1 * inv - mu1 * mu1;
        const float sc0 = gamma[0] * rsqrtf(v0 + 1e-5f);
        const float sc1 = gamma[1] * rsqrtf(v1 + 1e-5f);
        coef[0] = sc0; coef[1] = beta[0] - mu0 * sc0;
        coef[2] = sc1; coef[3] = beta[1] - mu1 * sc1;
    }
    __syncthreads();
    const float sc0 = coef[0], sh0 = coef[1], sc1 = coef[2], sh1 = coef[3];
    for (int i = t; i < B; i += 1024) {
        float2 v = ((const float2*)data)[i];
        v.x = fmaf(v.x, sc0, sh0);
        v.y = fmaf(v.y, sc1, sh1);
        ((float2*)data)[i] = v;
    }
}

extern "C" void kernel_launch(void* const* d_in, const int* in_sizes, int n_in,
                              void* d_out, int out_size, void* d_ws, size_t ws_size,
                              hipStream_t stream)
{
    (void)n_in; (void)out_size; (void)ws_size;
    const float* x   = (const float*)d_in[0];
    const float* w1  = (const float*)d_in[1];
    const float* b1  = (const float*)d_in[2];
    const float* w2  = (const float*)d_in[3];
    const float* b2  = (const float*)d_in[4];
    const float* w3  = (const float*)d_in[5];
    const float* b3  = (const float*)d_in[6];
    const float* gw1 = (const float*)d_in[7];
    const float* gw2 = (const float*)d_in[8];
    const float* rot = (const float*)d_in[9];
    const float* ent = (const float*)d_in[10];
    const float* rw  = (const float*)d_in[11];
    const float* rbv = (const float*)d_in[12];
    const float* cw  = (const float*)d_in[13];
    const float* cbv = (const float*)d_in[14];
    const float* gam = (const float*)d_in[15];
    const float* bet = (const float*)d_in[16];

    const int B = in_sizes[0] / (32 * 32);   // 4096

    _Float16* q16  = (_Float16*)d_ws;                 // [B][16]
    _Float16* k16  = q16 + (size_t)B * 16;            // [B][16]
    _Float16* g16  = k16 + (size_t)B * 16;            // [B][16]
    _Float16* gswz = g16 + (size_t)B * 16;            // [B/16][64][4]
    _Float16* w2f  = gswz + (size_t)B * 16;           // 1536 halves
    _Float16* w3f  = w2f + 1536;                      // 5120 halves
    h2v*      w1p  = (h2v*)(w3f + 5120);              // 24 pairs
    float*    w1t  = (float*)(w1p + 24);              // 24 floats
    float* pre = (float*)d_out;

    k_pack<<<1, 256, 0, stream>>>(w1, w2, w3, w2f, w3f, w1p, w1t);
    k_cnn<<<B, 256, 0, stream>>>(x, w1p, w1t, b1, w2f, b2, w3f, b3, gw1, gw2,
                                 rot, ent, q16, k16, g16, gswz);
    k_attn<<<B / 16, 256, 0, stream>>>(q16, k16, g16, gswz, rw, rbv, cw, cbv,
                                       pre, B);
    k_bn<<<1, 1024, 0, stream>>>(pre, gam, bet, B);
}

// Round 10
// 142.265 us; speedup vs baseline: 2.9731x; 1.1926x over previous
//
#include <hip/hip_runtime.h>
#include <math.h>

#define LOG2E 1.4426950408889634f

typedef _Float16 h2v __attribute__((ext_vector_type(2)));
typedef _Float16 h4  __attribute__((ext_vector_type(4)));
typedef _Float16 h8  __attribute__((ext_vector_type(8)));
typedef float    f4  __attribute__((ext_vector_type(4)));

__device__ __forceinline__ h2v pk(float a, float b) {
    return __builtin_bit_cast(h2v, __builtin_amdgcn_cvt_pkrtz(a, b));
}

__device__ __forceinline__ f4 mfma16x32(h8 a, h8 b, f4 c) {
    return __builtin_amdgcn_mfma_f32_16x16x32_f16(a, b, c, 0, 0, 0);
}

// Legacy (pre-gfx950) intrinsic name has NO underscore before f16.
__device__ __forceinline__ f4 mfma16x16(h4 a, h4 b, f4 c) {
    return __builtin_amdgcn_mfma_f32_16x16x16f16(a, b, c, 0, 0, 0);
}

__device__ __forceinline__ float fast_tanh(float x) {
    const float xc = fminf(fmaxf(x, -15.f), 15.f);
    const float t = exp2f(xc * (2.f * LOG2E));
    return (t - 1.f) * __builtin_amdgcn_rcpf(t + 1.f);
}

// ---------------------------------------------------------------------------
// Prelude: pack conv weights. w2f/w3f in MFMA A-fragment order (fp16);
// w1 as (col0,col1) h2 pairs + fp32 col2 for the conv1 dot2 path.
// ---------------------------------------------------------------------------
__global__ __launch_bounds__(256) void k_pack(
    const float* __restrict__ w1,
    const float* __restrict__ w2, const float* __restrict__ w3,
    _Float16* __restrict__ w2f, _Float16* __restrict__ w3f,
    h2v* __restrict__ w1p, float* __restrict__ w1t)
{
    if (threadIdx.x < 24) {
        const int oc = threadIdx.x / 3, ky = threadIdx.x % 3;
        w1p[threadIdx.x] = pk(w1[oc * 9 + ky * 3 + 0], w1[oc * 9 + ky * 3 + 1]);
        w1t[threadIdx.x] = w1[oc * 9 + ky * 3 + 2];
    }
    for (int idx = threadIdx.x; idx < 1536; idx += 256) {
        const int j = idx & 7;
        const int lane = (idx >> 3) & 63;
        const int c = idx >> 9;
        const int oc = lane & 15;
        const int s = c * 4 + (lane >> 4);
        w2f[idx] = (s < 9) ? (_Float16)w2[oc * 72 + j * 9 + s] : (_Float16)0.f;
    }
    for (int idx = threadIdx.x; idx < 5120; idx += 256) {
        const int j = idx & 7;
        const int lane = (idx >> 3) & 63;
        const int rest = idx >> 9;          // mt*5 + c
        const int mt = rest / 5;
        const int oc = mt * 16 + (lane & 15);
        const int kk = (lane >> 4) * 8 + j;
        const int ic = kk & 15;
        const int sh = (rest - mt * 5) * 2 + (kk >> 4);
        w3f[idx] = (sh < 9) ? (_Float16)w3[oc * 144 + ic * 9 + sh] : (_Float16)0.f;
    }
}

// ---------------------------------------------------------------------------
// Kernel 1 v7 (unchanged from R9): per-image CNN, conv1 fdot2, conv2/conv3
// MFMA, halo-only zeroing, conv3 single-shot staging.
// ---------------------------------------------------------------------------
__global__ __launch_bounds__(256) void k_cnn(
    const float* __restrict__ x,
    const h2v* __restrict__ w1p, const float* __restrict__ w1t,
    const float* __restrict__ b1,
    const _Float16* __restrict__ w2f, const float* __restrict__ b2,
    const _Float16* __restrict__ w3f, const float* __restrict__ b3,
    const float* __restrict__ gw1,
    const float* __restrict__ gw2,
    const float* __restrict__ rot,
    const float* __restrict__ ent,
    _Float16* __restrict__ q16, _Float16* __restrict__ k16,
    _Float16* __restrict__ g16, _Float16* __restrict__ gswz)
{
    __shared__ __align__(16) char smem[16384 + 5184 + 3200 + 576 + 128];
    float* xs   = (float*)smem;
    h8*  B2h8   = (h8*)smem;
    h8*  B3full = (h8*)smem;
    h8*  p1c    = (h8*)(smem + 16384);
    h8*  p2hc   = (h8*)(smem + 16384 + 5184);
    h4*  p2h4   = (h4*)(smem + 16384 + 5184);
    float* fsum = (float*)(smem + 16384 + 5184 + 3200);
    float* fs   = fsum + 64;
    float* as   = fs + 32;
    float* gs   = as + 32;
    float* qs   = gs + 16;
    float* ks   = qs + 16;

    const int t = threadIdx.x;
    const int b = blockIdx.x;
    const int lane = t & 63;
    const int w = __builtin_amdgcn_readfirstlane(t >> 6);
    const int nn = lane & 15;
    const int kq = lane >> 4;

    const h8 hzero = (h8)(_Float16)0.f;
    const f4 fzero = {0.f, 0.f, 0.f, 0.f};

    // ---- halo-only zeroing ----
    if (t < 132) {
        int r, c;
        if (t < 34)       { r = 0;  c = t; }
        else if (t < 68)  { r = 33; c = t - 34; }
        else if (t < 100) { r = t - 68 + 1;  c = 0; }
        else              { r = t - 100 + 1; c = 33; }
        xs[r * 34 + c] = 0.f;
    } else if (t < 200) {
        const int u = t - 132;
        int r, c;
        if (u < 18)      { r = 0;  c = u; }
        else if (u < 36) { r = 17; c = u - 18; }
        else if (u < 52) { r = u - 36 + 1; c = 0; }
        else             { r = u - 52 + 1; c = 17; }
        p1c[r * 18 + c] = hzero;
    } else if (t < 236) {
        const int u = t - 200;
        int r, c;
        if (u < 10)      { r = 0; c = u; }
        else if (u < 20) { r = 9; c = u - 10; }
        else if (u < 28) { r = u - 20 + 1; c = 0; }
        else             { r = u - 28 + 1; c = 9; }
        p2hc[(r * 10 + c) * 2 + 0] = hzero;
        p2hc[(r * 10 + c) * 2 + 1] = hzero;
    }
    {
        const float4 v = ((const float4*)(x + (size_t)b * 1024))[t];
        const int row = t >> 3;
        const int col = (t & 7) << 2;
        float* dst = &xs[(row + 1) * 34 + col + 1];
        dst[0] = v.x; dst[1] = v.y; dst[2] = v.z; dst[3] = v.w;
    }
    __syncthreads();

    // ---- stage 1: conv1 via fdot2 + relu + maxpool2 ----
    {
        const int px = t & 15, py = t >> 4;
        float pa[4][4];
        #pragma unroll
        for (int iy = 0; iy < 4; ++iy)
            #pragma unroll
            for (int ix = 0; ix < 4; ++ix)
                pa[iy][ix] = xs[(2 * py + iy) * 34 + (2 * px + ix)];
        h2v pA[4], pB[4];
        #pragma unroll
        for (int r = 0; r < 4; ++r) {
            pA[r] = pk(pa[r][0], pa[r][1]);
            pB[r] = pk(pa[r][1], pa[r][2]);
        }

        float r8[8];
        #pragma unroll
        for (int oc = 0; oc < 8; ++oc) {
            const h2v wp0 = w1p[oc * 3 + 0], wp1 = w1p[oc * 3 + 1], wp2 = w1p[oc * 3 + 2];
            const float wt0 = w1t[oc * 3 + 0], wt1 = w1t[oc * 3 + 1], wt2 = w1t[oc * 3 + 2];
            const float bb = b1[oc];
            float mx = -1e30f;
            #pragma unroll
            for (int sy = 0; sy < 2; ++sy) {
                float s0 = bb, s1 = bb;
                s0 = __builtin_amdgcn_fdot2(pA[sy],     wp0, s0, false);
                s0 = __builtin_amdgcn_fdot2(pA[sy + 1], wp1, s0, false);
                s0 = __builtin_amdgcn_fdot2(pA[sy + 2], wp2, s0, false);
                s0 = fmaf(pa[sy][2], wt0, s0);
                s0 = fmaf(pa[sy + 1][2], wt1, s0);
                s0 = fmaf(pa[sy + 2][2], wt2, s0);
                s1 = __builtin_amdgcn_fdot2(pB[sy],     wp0, s1, false);
                s1 = __builtin_amdgcn_fdot2(pB[sy + 1], wp1, s1, false);
                s1 = __builtin_amdgcn_fdot2(pB[sy + 2], wp2, s1, false);
                s1 = fmaf(pa[sy][3], wt0, s1);
                s1 = fmaf(pa[sy + 1][3], wt1, s1);
                s1 = fmaf(pa[sy + 2][3], wt2, s1);
                mx = fmaxf(mx, fmaxf(s0, s1));
            }
            r8[oc] = fmaxf(mx, 0.f);
        }
        union { h8 v; h2v p[4]; } u;
        #pragma unroll
        for (int ocp = 0; ocp < 4; ++ocp) u.p[ocp] = pk(r8[2 * ocp], r8[2 * ocp + 1]);
        p1c[(py + 1) * 18 + (px + 1)] = u.v;
    }

    h8 a2[3];
    #pragma unroll
    for (int c = 0; c < 3; ++c) a2[c] = ((const h8*)w2f)[c * 64 + lane];

    // ---- conv2 as GEMM, 3 K-chunks ----
    f4 accp[4] = {fzero, fzero, fzero, fzero};
    {
        const int y2 = t >> 4, x2 = t & 15;
        #pragma unroll
        for (int c = 0; c < 3; ++c) {
            __syncthreads();
            #pragma unroll
            for (int sl = 0; sl < 4; ++sl) {
                const int s = c * 4 + sl;
                h8 v = hzero;
                if (s < 9) {
                    const int ky = s / 3, kx = s % 3;
                    v = p1c[(y2 + ky) * 18 + (x2 + kx)];
                }
                B2h8[sl * 256 + t] = v;
            }
            __syncthreads();
            #pragma unroll
            for (int p = 0; p < 4; ++p) {
                const h8 bf = B2h8[kq * 256 + (4 * w + p) * 16 + nn];
                accp[p] = mfma16x32(a2[c], bf, accp[p]);
            }
        }
    }

    // ---- conv2 epilogue ----
    {
        float bq[4];
        #pragma unroll
        for (int r = 0; r < 4; ++r) bq[r] = b2[kq * 4 + r];
        #pragma unroll
        for (int i = 0; i < 2; ++i) {
            float m2[4];
            #pragma unroll
            for (int r = 0; r < 4; ++r) {
                const float v0 = fmaxf(accp[2 * i][r] + bq[r], 0.f);
                const float v1 = fmaxf(accp[2 * i + 1][r] + bq[r], 0.f);
                float mv = fmaxf(v0, v1);
                mv = fmaxf(mv, __shfl_xor(mv, 1));
                m2[r] = mv;
            }
            if ((lane & 1) == 0) {
                const int px = nn >> 1;
                const int py = 2 * w + i;
                union { h4 v; h2v p[2]; } u;
                u.p[0] = pk(m2[0], m2[1]);
                u.p[1] = pk(m2[2], m2[3]);
                p2h4[((py + 1) * 10 + (px + 1)) * 4 + kq] = u.v;
            }
        }
    }

    const int mt = w >> 1;
    const int nt0 = (w & 1) * 2;
    h8 a3[5];
    #pragma unroll
    for (int c = 0; c < 5; ++c) a3[c] = ((const h8*)w3f)[(mt * 5 + c) * 64 + lane];

    // ---- conv3: single-shot staging + barrier-free MFMA ----
    __syncthreads();
    #pragma unroll
    for (int ss = 0; ss < 5; ++ss) {
        const int idx = ss * 256 + t;
        const int slot = idx >> 6;
        const int pos = idx & 63;
        const int c = slot >> 2;
        const int kq3 = slot & 3;
        const int shv = 2 * c + (kq3 >> 1);
        const int hh = kq3 & 1;
        const int yy = pos >> 3, xx = pos & 7;
        h8 v = hzero;
        if (shv < 9) {
            const int ky = (shv * 11) >> 5;
            const int kx = shv - 3 * ky;
            v = p2hc[((yy + ky) * 10 + (xx + kx)) * 2 + hh];
        }
        B3full[slot * 64 + pos] = v;
    }
    __syncthreads();

    f4 acc3[2] = {fzero, fzero};
    #pragma unroll
    for (int c = 0; c < 5; ++c) {
        #pragma unroll
        for (int p = 0; p < 2; ++p) {
            const h8 bf = B3full[(c * 4 + kq) * 64 + (nt0 + p) * 16 + nn];
            acc3[p] = mfma16x32(a3[c], bf, acc3[p]);
        }
    }

    // ---- conv3 epilogue ----
    {
        float bq[4];
        #pragma unroll
        for (int r = 0; r < 4; ++r) bq[r] = b3[mt * 16 + kq * 4 + r];
        float sv[4];
        #pragma unroll
        for (int r = 0; r < 4; ++r) {
            float s = fmaxf(acc3[0][r] + bq[r], 0.f) + fmaxf(acc3[1][r] + bq[r], 0.f);
            #pragma unroll
            for (int off = 1; off < 16; off <<= 1) s += __shfl_xor(s, off);
            sv[r] = s;
        }
        if (nn == 0) {
            const f4 pack = {sv[0], sv[1], sv[2], sv[3]};
            ((f4*)fsum)[mt * 8 + (w & 1) * 4 + kq] = pack;
        }
    }
    __syncthreads();

    // ---- stage 4: mean + MLP head ----
    if (t < 32)
        fs[t] = (fsum[(t >> 4) * 32 + (t & 15)] +
                 fsum[(t >> 4) * 32 + 16 + (t & 15)]) * (1.f / 64.f);
    __syncthreads();
    if (t < 32) {
        float s = 0.f;
        #pragma unroll
        for (int j = 0; j < 32; ++j) s = fmaf(gw1[t * 32 + j], fs[j], s);
        as[t] = fast_tanh(s);
    }
    __syncthreads();
    if (t < 16) {
        float s = 0.f;
        #pragma unroll
        for (int j = 0; j < 32; ++j) s = fmaf(gw2[t * 32 + j], as[j], s);
        gs[t] = fast_tanh(s);
    }
    __syncthreads();
    if (t < 16) {
        const int r = t >> 2, c = t & 3;
        float qv = 0.f, kv = 0.f;
        #pragma unroll
        for (int j = 0; j < 4; ++j) {
            qv = fmaf(gs[r * 4 + j], rot[j * 4 + c], qv);
            kv = fmaf(gs[r * 4 + j], rot[c * 4 + j], kv);
        }
        qs[t] = qv;
        ks[t] = kv;
    }
    __syncthreads();
    if (t < 8) {
        const float temp = (cosf(ent[0]) + cosf(ent[1]) + cosf(ent[2])) * (1.f / 3.f);
        const float scale = temp * 0.25f;
        ((h2v*)q16)[b * 8 + t] = pk(qs[2 * t] * scale, qs[2 * t + 1] * scale);
        ((h2v*)k16)[b * 8 + t] = pk(ks[2 * t], ks[2 * t + 1]);
        ((h2v*)g16)[b * 8 + t] = pk(gs[2 * t], gs[2 * t + 1]);
    }
    if (t < 16) {
        const int tile = b >> 4, lc = b & 15;
        gswz[tile * 256 + (((lc >> 2) * 16) + t) * 4 + (lc & 3)] = (_Float16)gs[t];
    }
}

// ---------------------------------------------------------------------------
// Kernel 2 v5: MFMA flash attention, 1024 threads (16 waves) per block.
// Wave w covers cols [w*256, w*256+256) -> 16 serial iters (was 64);
// 4 waves/SIMD hide the load->MFMA->exp->MFMA latency chain.
// ---------------------------------------------------------------------------
__global__ __launch_bounds__(1024) void k_attn(
    const _Float16* __restrict__ q16, const _Float16* __restrict__ k16,
    const _Float16* __restrict__ g16, const _Float16* __restrict__ gswz,
    const float* __restrict__ rw, const float* __restrict__ rb,
    const float* __restrict__ cw, const float* __restrict__ cb,
    float* __restrict__ outp, int B)
{
    __shared__ f4 lO[16][64];
    __shared__ float lm[16][16];
    __shared__ float ll[16][16];

    const int t = threadIdx.x;
    const int lane = t & 63;
    const int w = t >> 6;               // 0..15
    const int rt = blockIdx.x;          // row tile (16 rows)
    const int r = lane & 15;
    const int q = lane >> 4;
    const f4 fzero = {0.f, 0.f, 0.f, 0.f};

    // Q B-fragment: lane holds Q[rt*16+r][d=q*4+j] (scale pre-folded)
    const h4 qf = *(const h4*)(q16 + ((size_t)(rt * 16 + r)) * 16 + q * 4);

    float m = -1e30f, lp = 0.f;
    f4 O = fzero;

    const int strip = B >> 4;           // 256 cols per wave
    const int cbeg = w * strip;
    for (int ci = 0; ci < strip; ci += 16) {
        const int c0 = cbeg + ci;
        const h4 kf = *(const h4*)(k16 + ((size_t)(c0 + r)) * 16 + q * 4);
        const f4 st = mfma16x16(kf, qf, fzero);

        float mx = fmaxf(fmaxf(st[0], st[1]), fmaxf(st[2], st[3]));
        mx = fmaxf(mx, __shfl_xor(mx, 16));
        mx = fmaxf(mx, __shfl_xor(mx, 32));
        if (__ballot(mx > m)) {
            const float mn = fmaxf(m, mx);
            const float a = exp2f((m - mn) * LOG2E);
            lp *= a;
            O[0] *= a; O[1] *= a; O[2] *= a; O[3] *= a;
            m = mn;
        }
        const float p0 = exp2f((st[0] - m) * LOG2E);
        const float p1 = exp2f((st[1] - m) * LOG2E);
        const float p2 = exp2f((st[2] - m) * LOG2E);
        const float p3 = exp2f((st[3] - m) * LOG2E);
        lp += (p0 + p1) + (p2 + p3);

        union { h4 v; h2v p[2]; } u;
        u.p[0] = pk(p0, p1);
        u.p[1] = pk(p2, p3);
        const h4 gf = *(const h4*)(gswz + (size_t)((c0 >> 4)) * 256 + lane * 4);
        O = mfma16x16(gf, u.v, O);
    }
    lp += __shfl_xor(lp, 16);
    lp += __shfl_xor(lp, 32);

    lO[w][lane] = O;
    if (lane < 16) { lm[w][lane] = m; ll[w][lane] = lp; }
    __syncthreads();

    // ---- 16-way cross-wave merge + fused reduce/cls epilogue (wave 0) ----
    if (w == 0) {
        float M = lm[0][r];
        #pragma unroll
        for (int ww = 1; ww < 16; ++ww) M = fmaxf(M, lm[ww][r]);
        float L = 0.f;
        f4 Om = fzero;
        #pragma unroll
        for (int ww = 0; ww < 16; ++ww) {
            const float f = exp2f((lm[ww][r] - M) * LOG2E);
            L = fmaf(ll[ww][r], f, L);
            const f4 ow = lO[ww][lane];
            Om[0] = fmaf(ow[0], f, Om[0]);
            Om[1] = fmaf(ow[1], f, Om[1]);
            Om[2] = fmaf(ow[2], f, Om[2]);
            Om[3] = fmaf(ow[3], f, Om[3]);
        }
        const float il = 1.f / L;
        const h4 gr = *(const h4*)(g16 + ((size_t)(rt * 16 + r)) * 16 + q * 4);

        float rv[2];
        #pragma unroll
        for (int c = 0; c < 2; ++c) {
            float s = 0.f;
            #pragma unroll
            for (int j = 0; j < 4; ++j) {
                s = fmaf((float)gr[j], rw[c * 32 + q * 4 + j], s);
                s = fmaf(Om[j] * il, rw[c * 32 + 16 + q * 4 + j], s);
            }
            s += __shfl_xor(s, 16);
            s += __shfl_xor(s, 32);
            rv[c] = s + rb[c];
        }
        if (q == 0) {
            // fraud layers (all-zero params) are identity; classifier:
            float2 o;
            o.x = cb[0] + cw[0] * rv[0] + cw[1] * rv[1];
            o.y = cb[1] + cw[2] * rv[0] + cw[3] * rv[1];
            ((float2*)outp)[rt * 16 + r] = o;
        }
    }
}

// ---------------------------------------------------------------------------
// Kernel 3: BatchNorm1d(2), batch stats, in-place on d_out.
// ---------------------------------------------------------------------------
__global__ __launch_bounds__(1024) void k_bn(
    float* __restrict__ data, const float* __restrict__ gamma,
    const float* __restrict__ beta, int B)
{
    __shared__ float red[16][4];
    __shared__ float coef[4];
    const int t = threadIdx.x;
    float s0 = 0.f, s1 = 0.f, q0 = 0.f, q1 = 0.f;
    for (int i = t; i < B; i += 1024) {
        const float2 v = ((const float2*)data)[i];
        s0 += v.x; q0 += v.x * v.x;
        s1 += v.y; q1 += v.y * v.y;
    }
    #pragma unroll
    for (int off = 32; off; off >>= 1) {
        s0 += __shfl_xor(s0, off); q0 += __shfl_xor(q0, off);
        s1 += __shfl_xor(s1, off); q1 += __shfl_xor(q1, off);
    }
    if ((t & 63) == 0) {
        red[t >> 6][0] = s0; red[t >> 6][1] = q0;
        red[t >> 6][2] = s1; red[t >> 6][3] = q1;
    }
    __syncthreads();
    if (t == 0) {
        float S0 = 0.f, Q0 = 0.f, S1 = 0.f, Q1 = 0.f;
        for (int w = 0; w < 16; ++w) {
            S0 += red[w][0]; Q0 += red[w][1]; S1 += red[w][2]; Q1 += red[w][3];
        }
        const float inv = 1.f / (float)B;
        const float mu0 = S0 * inv, mu1 = S1 * inv;
        const float v0 = Q0 * inv - mu0 * mu0;
        const float v1 = Q1 * inv - mu1 * mu1;
        const float sc0 = gamma[0] * rsqrtf(v0 + 1e-5f);
        const float sc1 = gamma[1] * rsqrtf(v1 + 1e-5f);
        coef[0] = sc0; coef[1] = beta[0] - mu0 * sc0;
        coef[2] = sc1; coef[3] = beta[1] - mu1 * sc1;
    }
    __syncthreads();
    const float sc0 = coef[0], sh0 = coef[1], sc1 = coef[2], sh1 = coef[3];
    for (int i = t; i < B; i += 1024) {
        float2 v = ((const float2*)data)[i];
        v.x = fmaf(v.x, sc0, sh0);
        v.y = fmaf(v.y, sc1, sh1);
        ((float2*)data)[i] = v;
    }
}

extern "C" void kernel_launch(void* const* d_in, const int* in_sizes, int n_in,
                              void* d_out, int out_size, void* d_ws, size_t ws_size,
                              hipStream_t stream)
{
    (void)n_in; (void)out_size; (void)ws_size;
    const float* x   = (const float*)d_in[0];
    const float* w1  = (const float*)d_in[1];
    const float* b1  = (const float*)d_in[2];
    const float* w2  = (const float*)d_in[3];
    const float* b2  = (const float*)d_in[4];
    const float* w3  = (const float*)d_in[5];
    const float* b3  = (const float*)d_in[6];
    const float* gw1 = (const float*)d_in[7];
    const float* gw2 = (const float*)d_in[8];
    const float* rot = (const float*)d_in[9];
    const float* ent = (const float*)d_in[10];
    const float* rw  = (const float*)d_in[11];
    const float* rbv = (const float*)d_in[12];
    const float* cw  = (const float*)d_in[13];
    const float* cbv = (const float*)d_in[14];
    const float* gam = (const float*)d_in[15];
    const float* bet = (const float*)d_in[16];

    const int B = in_sizes[0] / (32 * 32);   // 4096

    _Float16* q16  = (_Float16*)d_ws;                 // [B][16]
    _Float16* k16  = q16 + (size_t)B * 16;            // [B][16]
    _Float16* g16  = k16 + (size_t)B * 16;            // [B][16]
    _Float16* gswz = g16 + (size_t)B * 16;            // [B/16][64][4]
    _Float16* w2f  = gswz + (size_t)B * 16;           // 1536 halves
    _Float16* w3f  = w2f + 1536;                      // 5120 halves
    h2v*      w1p  = (h2v*)(w3f + 5120);              // 24 pairs
    float*    w1t  = (float*)(w1p + 24);              // 24 floats
    float* pre = (float*)d_out;

    k_pack<<<1, 256, 0, stream>>>(w1, w2, w3, w2f, w3f, w1p, w1t);
    k_cnn<<<B, 256, 0, stream>>>(x, w1p, w1t, b1, w2f, b2, w3f, b3, gw1, gw2,
                                 rot, ent, q16, k16, g16, gswz);
    k_attn<<<B / 16, 1024, 0, stream>>>(q16, k16, g16, gswz, rw, rbv, cw, cbv,
                                        pre, B);
    k_bn<<<1, 1024, 0, stream>>>(pre, gam, bet, B);
}

// Round 11
// 140.195 us; speedup vs baseline: 3.0170x; 1.0148x over previous
//
#include <hip/hip_runtime.h>
#include <math.h>

#define LOG2E 1.4426950408889634f

typedef _Float16 h2v __attribute__((ext_vector_type(2)));
typedef _Float16 h4  __attribute__((ext_vector_type(4)));
typedef _Float16 h8  __attribute__((ext_vector_type(8)));
typedef float    f4  __attribute__((ext_vector_type(4)));

__device__ __forceinline__ h2v pk(float a, float b) {
    return __builtin_bit_cast(h2v, __builtin_amdgcn_cvt_pkrtz(a, b));
}

__device__ __forceinline__ f4 mfma16x32(h8 a, h8 b, f4 c) {
    return __builtin_amdgcn_mfma_f32_16x16x32_f16(a, b, c, 0, 0, 0);
}

// Legacy (pre-gfx950) intrinsic name has NO underscore before f16.
__device__ __forceinline__ f4 mfma16x16(h4 a, h4 b, f4 c) {
    return __builtin_amdgcn_mfma_f32_16x16x16f16(a, b, c, 0, 0, 0);
}

__device__ __forceinline__ float fast_tanh(float x) {
    const float xc = fminf(fmaxf(x, -15.f), 15.f);
    const float t = exp2f(xc * (2.f * LOG2E));
    return (t - 1.f) * __builtin_amdgcn_rcpf(t + 1.f);
}

// ---------------------------------------------------------------------------
// Prelude: pack conv weights. w2f/w3f in MFMA A-fragment order (fp16);
// w1 as (col0,col1) h2 pairs + fp32 col2 for the conv1 dot2 path.
// ---------------------------------------------------------------------------
__global__ __launch_bounds__(256) void k_pack(
    const float* __restrict__ w1,
    const float* __restrict__ w2, const float* __restrict__ w3,
    _Float16* __restrict__ w2f, _Float16* __restrict__ w3f,
    h2v* __restrict__ w1p, float* __restrict__ w1t)
{
    if (threadIdx.x < 24) {
        const int oc = threadIdx.x / 3, ky = threadIdx.x % 3;
        w1p[threadIdx.x] = pk(w1[oc * 9 + ky * 3 + 0], w1[oc * 9 + ky * 3 + 1]);
        w1t[threadIdx.x] = w1[oc * 9 + ky * 3 + 2];
    }
    for (int idx = threadIdx.x; idx < 1536; idx += 256) {
        const int j = idx & 7;
        const int lane = (idx >> 3) & 63;
        const int c = idx >> 9;
        const int oc = lane & 15;
        const int s = c * 4 + (lane >> 4);
        w2f[idx] = (s < 9) ? (_Float16)w2[oc * 72 + j * 9 + s] : (_Float16)0.f;
    }
    for (int idx = threadIdx.x; idx < 5120; idx += 256) {
        const int j = idx & 7;
        const int lane = (idx >> 3) & 63;
        const int rest = idx >> 9;          // mt*5 + c
        const int mt = rest / 5;
        const int oc = mt * 16 + (lane & 15);
        const int kk = (lane >> 4) * 8 + j;
        const int ic = kk & 15;
        const int sh = (rest - mt * 5) * 2 + (kk >> 4);
        w3f[idx] = (sh < 9) ? (_Float16)w3[oc * 144 + ic * 9 + sh] : (_Float16)0.f;
    }
}

// ---------------------------------------------------------------------------
// Kernel 1 v8: per-image CNN. conv2/conv3 MFMA B-fragments read DIRECTLY
// from the p1c/p2hc cell arrays (one ds_read_b128 each) — no staging
// buffers, barriers 12 -> 7, LDS 25.9 KB -> 13.7 KB (2x blocks/CU).
// ---------------------------------------------------------------------------
__global__ __launch_bounds__(256) void k_cnn(
    const float* __restrict__ x,
    const h2v* __restrict__ w1p, const float* __restrict__ w1t,
    const float* __restrict__ b1,
    const _Float16* __restrict__ w2f, const float* __restrict__ b2,
    const _Float16* __restrict__ w3f, const float* __restrict__ b3,
    const float* __restrict__ gw1,
    const float* __restrict__ gw2,
    const float* __restrict__ rot,
    const float* __restrict__ ent,
    _Float16* __restrict__ q16, _Float16* __restrict__ k16,
    _Float16* __restrict__ g16, _Float16* __restrict__ gswz)
{
    __shared__ __align__(16) char smem[4624 + 5184 + 3200 + 256 + 512];
    float* xs   = (float*)smem;                       // 34x34 fp32
    h8*  p1c    = (h8*)(smem + 4624);                 // [18][18] cells of 8 halves
    h8*  p2hc   = (h8*)(smem + 4624 + 5184);          // [10][10] cells, 2 h8 each
    h4*  p2h4   = (h4*)(smem + 4624 + 5184);
    float* fsum = (float*)(smem + 4624 + 5184 + 3200);    // 64 floats
    float* fs   = fsum + 64;
    float* as   = fs + 32;
    float* gs   = as + 32;
    float* qs   = gs + 16;
    float* ks   = qs + 16;

    const int t = threadIdx.x;
    const int b = blockIdx.x;
    const int lane = t & 63;
    const int w = __builtin_amdgcn_readfirstlane(t >> 6);
    const int nn = lane & 15;
    const int kq = lane >> 4;

    const h8 hzero = (h8)(_Float16)0.f;
    const f4 fzero = {0.f, 0.f, 0.f, 0.f};

    // ---- halo-only zeroing (interiors fully overwritten) ----
    if (t < 132) {
        int r, c;
        if (t < 34)       { r = 0;  c = t; }
        else if (t < 68)  { r = 33; c = t - 34; }
        else if (t < 100) { r = t - 68 + 1;  c = 0; }
        else              { r = t - 100 + 1; c = 33; }
        xs[r * 34 + c] = 0.f;
    } else if (t < 200) {
        const int u = t - 132;
        int r, c;
        if (u < 18)      { r = 0;  c = u; }
        else if (u < 36) { r = 17; c = u - 18; }
        else if (u < 52) { r = u - 36 + 1; c = 0; }
        else             { r = u - 52 + 1; c = 17; }
        p1c[r * 18 + c] = hzero;
    } else if (t < 236) {
        const int u = t - 200;
        int r, c;
        if (u < 10)      { r = 0; c = u; }
        else if (u < 20) { r = 9; c = u - 10; }
        else if (u < 28) { r = u - 20 + 1; c = 0; }
        else             { r = u - 28 + 1; c = 9; }
        p2hc[(r * 10 + c) * 2 + 0] = hzero;
        p2hc[(r * 10 + c) * 2 + 1] = hzero;
    }
    {
        const float4 v = ((const float4*)(x + (size_t)b * 1024))[t];
        const int row = t >> 3;
        const int col = (t & 7) << 2;
        float* dst = &xs[(row + 1) * 34 + col + 1];
        dst[0] = v.x; dst[1] = v.y; dst[2] = v.z; dst[3] = v.w;
    }
    __syncthreads();

    // ---- stage 1: conv1 via fdot2 + relu + maxpool2 -> p1 cells ----
    {
        const int px = t & 15, py = t >> 4;
        float pa[4][4];
        #pragma unroll
        for (int iy = 0; iy < 4; ++iy)
            #pragma unroll
            for (int ix = 0; ix < 4; ++ix)
                pa[iy][ix] = xs[(2 * py + iy) * 34 + (2 * px + ix)];
        h2v pA[4], pB[4];
        #pragma unroll
        for (int r = 0; r < 4; ++r) {
            pA[r] = pk(pa[r][0], pa[r][1]);
            pB[r] = pk(pa[r][1], pa[r][2]);
        }

        float r8[8];
        #pragma unroll
        for (int oc = 0; oc < 8; ++oc) {
            const h2v wp0 = w1p[oc * 3 + 0], wp1 = w1p[oc * 3 + 1], wp2 = w1p[oc * 3 + 2];
            const float wt0 = w1t[oc * 3 + 0], wt1 = w1t[oc * 3 + 1], wt2 = w1t[oc * 3 + 2];
            const float bb = b1[oc];
            float mx = -1e30f;
            #pragma unroll
            for (int sy = 0; sy < 2; ++sy) {
                float s0 = bb, s1 = bb;
                s0 = __builtin_amdgcn_fdot2(pA[sy],     wp0, s0, false);
                s0 = __builtin_amdgcn_fdot2(pA[sy + 1], wp1, s0, false);
                s0 = __builtin_amdgcn_fdot2(pA[sy + 2], wp2, s0, false);
                s0 = fmaf(pa[sy][2], wt0, s0);
                s0 = fmaf(pa[sy + 1][2], wt1, s0);
                s0 = fmaf(pa[sy + 2][2], wt2, s0);
                s1 = __builtin_amdgcn_fdot2(pB[sy],     wp0, s1, false);
                s1 = __builtin_amdgcn_fdot2(pB[sy + 1], wp1, s1, false);
                s1 = __builtin_amdgcn_fdot2(pB[sy + 2], wp2, s1, false);
                s1 = fmaf(pa[sy][3], wt0, s1);
                s1 = fmaf(pa[sy + 1][3], wt1, s1);
                s1 = fmaf(pa[sy + 2][3], wt2, s1);
                mx = fmaxf(mx, fmaxf(s0, s1));
            }
            r8[oc] = fmaxf(mx, 0.f);
        }
        union { h8 v; h2v p[4]; } u;
        #pragma unroll
        for (int ocp = 0; ocp < 4; ++ocp) u.p[ocp] = pk(r8[2 * ocp], r8[2 * ocp + 1]);
        p1c[(py + 1) * 18 + (px + 1)] = u.v;
    }

    h8 a2[3];
    #pragma unroll
    for (int c = 0; c < 3; ++c) a2[c] = ((const h8*)w2f)[c * 64 + lane];

    __syncthreads();   // p1c ready

    // ---- conv2(8->16) as GEMM: B-fragments read directly from p1c ----
    //  B[col=(4w+p)*16+nn][k=c*32+kq*8+j] = p1c[(4w+p+ky)*18 + (nn+kx)][j],
    //  (ky,kx) from s = c*4+kq; zero for s >= 9.  No staging, no barriers.
    f4 accp[4] = {fzero, fzero, fzero, fzero};
    #pragma unroll
    for (int c = 0; c < 3; ++c) {
        const int s = c * 4 + kq;
        const int ky = (s < 9) ? s / 3 : 0;
        const int kx = (s < 9) ? s % 3 : 0;
        #pragma unroll
        for (int p = 0; p < 4; ++p) {
            h8 bf = hzero;
            if (s < 9) bf = p1c[(4 * w + p + ky) * 18 + (nn + kx)];
            accp[p] = mfma16x32(a2[c], bf, accp[p]);
        }
    }

    // ---- conv2 epilogue: +bias, relu, 2x2 maxpool -> p2 cells ----
    {
        float bq[4];
        #pragma unroll
        for (int r = 0; r < 4; ++r) bq[r] = b2[kq * 4 + r];
        #pragma unroll
        for (int i = 0; i < 2; ++i) {
            float m2[4];
            #pragma unroll
            for (int r = 0; r < 4; ++r) {
                const float v0 = fmaxf(accp[2 * i][r] + bq[r], 0.f);
                const float v1 = fmaxf(accp[2 * i + 1][r] + bq[r], 0.f);
                float mv = fmaxf(v0, v1);
                mv = fmaxf(mv, __shfl_xor(mv, 1));
                m2[r] = mv;
            }
            if ((lane & 1) == 0) {
                const int px = nn >> 1;
                const int py = 2 * w + i;
                union { h4 v; h2v p[2]; } u;
                u.p[0] = pk(m2[0], m2[1]);
                u.p[1] = pk(m2[2], m2[3]);
                p2h4[((py + 1) * 10 + (px + 1)) * 4 + kq] = u.v;
            }
        }
    }

    const int mt = w >> 1;
    const int nt0 = (w & 1) * 2;
    h8 a3[5];
    #pragma unroll
    for (int c = 0; c < 5; ++c) a3[c] = ((const h8*)w3f)[(mt * 5 + c) * 64 + lane];

    __syncthreads();   // p2hc ready

    // ---- conv3(16->32) as GEMM: B-fragments read directly from p2hc ----
    //  slot = c*4+kq -> shv = 2c+(kq>>1), hh = kq&1; pos = (nt0+p)*16+nn.
    f4 acc3[2] = {fzero, fzero};
    #pragma unroll
    for (int c = 0; c < 5; ++c) {
        const int shv = 2 * c + (kq >> 1);
        const int hh = kq & 1;
        const int ky = (shv < 9) ? ((shv * 11) >> 5) : 0;
        const int kx = (shv < 9) ? (shv - 3 * ky) : 0;
        #pragma unroll
        for (int p = 0; p < 2; ++p) {
            const int pos = (nt0 + p) * 16 + nn;
            const int yy = pos >> 3, xx = pos & 7;
            h8 bf = hzero;
            if (shv < 9) bf = p2hc[((yy + ky) * 10 + (xx + kx)) * 2 + hh];
            acc3[p] = mfma16x32(a3[c], bf, acc3[p]);
        }
    }

    // ---- conv3 epilogue: +bias, relu, spatial sum ----
    {
        float bq[4];
        #pragma unroll
        for (int r = 0; r < 4; ++r) bq[r] = b3[mt * 16 + kq * 4 + r];
        float sv[4];
        #pragma unroll
        for (int r = 0; r < 4; ++r) {
            float s = fmaxf(acc3[0][r] + bq[r], 0.f) + fmaxf(acc3[1][r] + bq[r], 0.f);
            #pragma unroll
            for (int off = 1; off < 16; off <<= 1) s += __shfl_xor(s, off);
            sv[r] = s;
        }
        if (nn == 0) {
            const f4 pack = {sv[0], sv[1], sv[2], sv[3]};
            ((f4*)fsum)[mt * 8 + (w & 1) * 4 + kq] = pack;
        }
    }
    __syncthreads();

    // ---- stage 4: mean + MLP head ----
    if (t < 32)
        fs[t] = (fsum[(t >> 4) * 32 + (t & 15)] +
                 fsum[(t >> 4) * 32 + 16 + (t & 15)]) * (1.f / 64.f);
    __syncthreads();
    if (t < 32) {
        float s = 0.f;
        #pragma unroll
        for (int j = 0; j < 32; ++j) s = fmaf(gw1[t * 32 + j], fs[j], s);
        as[t] = fast_tanh(s);
    }
    __syncthreads();
    if (t < 16) {
        float s = 0.f;
        #pragma unroll
        for (int j = 0; j < 32; ++j) s = fmaf(gw2[t * 32 + j], as[j], s);
        gs[t] = fast_tanh(s);
    }
    __syncthreads();
    if (t < 16) {
        const int r = t >> 2, c = t & 3;
        float qv = 0.f, kv = 0.f;
        #pragma unroll
        for (int j = 0; j < 4; ++j) {
            qv = fmaf(gs[r * 4 + j], rot[j * 4 + c], qv);
            kv = fmaf(gs[r * 4 + j], rot[c * 4 + j], kv);
        }
        qs[t] = qv;
        ks[t] = kv;
    }
    __syncthreads();
    if (t < 8) {
        const float temp = (cosf(ent[0]) + cosf(ent[1]) + cosf(ent[2])) * (1.f / 3.f);
        const float scale = temp * 0.25f;
        ((h2v*)q16)[b * 8 + t] = pk(qs[2 * t] * scale, qs[2 * t + 1] * scale);
        ((h2v*)k16)[b * 8 + t] = pk(ks[2 * t], ks[2 * t + 1]);
        ((h2v*)g16)[b * 8 + t] = pk(gs[2 * t], gs[2 * t + 1]);
    }
    if (t < 16) {
        const int tile = b >> 4, lc = b & 15;
        gswz[tile * 256 + (((lc >> 2) * 16) + t) * 4 + (lc & 3)] = (_Float16)gs[t];
    }
}

// ---------------------------------------------------------------------------
// Kernel 2 v5 (unchanged from R10): MFMA flash attention, 16 waves/block.
// ---------------------------------------------------------------------------
__global__ __launch_bounds__(1024) void k_attn(
    const _Float16* __restrict__ q16, const _Float16* __restrict__ k16,
    const _Float16* __restrict__ g16, const _Float16* __restrict__ gswz,
    const float* __restrict__ rw, const float* __restrict__ rb,
    const float* __restrict__ cw, const float* __restrict__ cb,
    float* __restrict__ outp, int B)
{
    __shared__ f4 lO[16][64];
    __shared__ float lm[16][16];
    __shared__ float ll[16][16];

    const int t = threadIdx.x;
    const int lane = t & 63;
    const int w = t >> 6;
    const int rt = blockIdx.x;
    const int r = lane & 15;
    const int q = lane >> 4;
    const f4 fzero = {0.f, 0.f, 0.f, 0.f};

    const h4 qf = *(const h4*)(q16 + ((size_t)(rt * 16 + r)) * 16 + q * 4);

    float m = -1e30f, lp = 0.f;
    f4 O = fzero;

    const int strip = B >> 4;
    const int cbeg = w * strip;
    for (int ci = 0; ci < strip; ci += 16) {
        const int c0 = cbeg + ci;
        const h4 kf = *(const h4*)(k16 + ((size_t)(c0 + r)) * 16 + q * 4);
        const f4 st = mfma16x16(kf, qf, fzero);

        float mx = fmaxf(fmaxf(st[0], st[1]), fmaxf(st[2], st[3]));
        mx = fmaxf(mx, __shfl_xor(mx, 16));
        mx = fmaxf(mx, __shfl_xor(mx, 32));
        if (__ballot(mx > m)) {
            const float mn = fmaxf(m, mx);
            const float a = exp2f((m - mn) * LOG2E);
            lp *= a;
            O[0] *= a; O[1] *= a; O[2] *= a; O[3] *= a;
            m = mn;
        }
        const float p0 = exp2f((st[0] - m) * LOG2E);
        const float p1 = exp2f((st[1] - m) * LOG2E);
        const float p2 = exp2f((st[2] - m) * LOG2E);
        const float p3 = exp2f((st[3] - m) * LOG2E);
        lp += (p0 + p1) + (p2 + p3);

        union { h4 v; h2v p[2]; } u;
        u.p[0] = pk(p0, p1);
        u.p[1] = pk(p2, p3);
        const h4 gf = *(const h4*)(gswz + (size_t)((c0 >> 4)) * 256 + lane * 4);
        O = mfma16x16(gf, u.v, O);
    }
    lp += __shfl_xor(lp, 16);
    lp += __shfl_xor(lp, 32);

    lO[w][lane] = O;
    if (lane < 16) { lm[w][lane] = m; ll[w][lane] = lp; }
    __syncthreads();

    if (w == 0) {
        float M = lm[0][r];
        #pragma unroll
        for (int ww = 1; ww < 16; ++ww) M = fmaxf(M, lm[ww][r]);
        float L = 0.f;
        f4 Om = fzero;
        #pragma unroll
        for (int ww = 0; ww < 16; ++ww) {
            const float f = exp2f((lm[ww][r] - M) * LOG2E);
            L = fmaf(ll[ww][r], f, L);
            const f4 ow = lO[ww][lane];
            Om[0] = fmaf(ow[0], f, Om[0]);
            Om[1] = fmaf(ow[1], f, Om[1]);
            Om[2] = fmaf(ow[2], f, Om[2]);
            Om[3] = fmaf(ow[3], f, Om[3]);
        }
        const float il = 1.f / L;
        const h4 gr = *(const h4*)(g16 + ((size_t)(rt * 16 + r)) * 16 + q * 4);

        float rv[2];
        #pragma unroll
        for (int c = 0; c < 2; ++c) {
            float s = 0.f;
            #pragma unroll
            for (int j = 0; j < 4; ++j) {
                s = fmaf((float)gr[j], rw[c * 32 + q * 4 + j], s);
                s = fmaf(Om[j] * il, rw[c * 32 + 16 + q * 4 + j], s);
            }
            s += __shfl_xor(s, 16);
            s += __shfl_xor(s, 32);
            rv[c] = s + rb[c];
        }
        if (q == 0) {
            float2 o;
            o.x = cb[0] + cw[0] * rv[0] + cw[1] * rv[1];
            o.y = cb[1] + cw[2] * rv[0] + cw[3] * rv[1];
            ((float2*)outp)[rt * 16 + r] = o;
        }
    }
}

// ---------------------------------------------------------------------------
// Kernel 3: BatchNorm1d(2), batch stats, in-place on d_out.
// ---------------------------------------------------------------------------
__global__ __launch_bounds__(1024) void k_bn(
    float* __restrict__ data, const float* __restrict__ gamma,
    const float* __restrict__ beta, int B)
{
    __shared__ float red[16][4];
    __shared__ float coef[4];
    const int t = threadIdx.x;
    float s0 = 0.f, s1 = 0.f, q0 = 0.f, q1 = 0.f;
    for (int i = t; i < B; i += 1024) {
        const float2 v = ((const float2*)data)[i];
        s0 += v.x; q0 += v.x * v.x;
        s1 += v.y; q1 += v.y * v.y;
    }
    #pragma unroll
    for (int off = 32; off; off >>= 1) {
        s0 += __shfl_xor(s0, off); q0 += __shfl_xor(q0, off);
        s1 += __shfl_xor(s1, off); q1 += __shfl_xor(q1, off);
    }
    if ((t & 63) == 0) {
        red[t >> 6][0] = s0; red[t >> 6][1] = q0;
        red[t >> 6][2] = s1; red[t >> 6][3] = q1;
    }
    __syncthreads();
    if (t == 0) {
        float S0 = 0.f, Q0 = 0.f, S1 = 0.f, Q1 = 0.f;
        for (int w = 0; w < 16; ++w) {
            S0 += red[w][0]; Q0 += red[w][1]; S1 += red[w][2]; Q1 += red[w][3];
        }
        const float inv = 1.f / (float)B;
        const float mu0 = S0 * inv, mu1 = S1 * inv;
        const float v0 = Q0 * inv - mu0 * mu0;
        const float v1 = Q1 * inv - mu1 * mu1;
        const float sc0 = gamma[0] * rsqrtf(v0 + 1e-5f);
        const float sc1 = gamma[1] * rsqrtf(v1 + 1e-5f);
        coef[0] = sc0; coef[1] = beta[0] - mu0 * sc0;
        coef[2] = sc1; coef[3] = beta[1] - mu1 * sc1;
    }
    __syncthreads();
    const float sc0 = coef[0], sh0 = coef[1], sc1 = coef[2], sh1 = coef[3];
    for (int i = t; i < B; i += 1024) {
        float2 v = ((const float2*)data)[i];
        v.x = fmaf(v.x, sc0, sh0);
        v.y = fmaf(v.y, sc1, sh1);
        ((float2*)data)[i] = v;
    }
}

extern "C" void kernel_launch(void* const* d_in, const int* in_sizes, int n_in,
                              void* d_out, int out_size, void* d_ws, size_t ws_size,
                              hipStream_t stream)
{
    (void)n_in; (void)out_size; (void)ws_size;
    const float* x   = (const float*)d_in[0];
    const float* w1  = (const float*)d_in[1];
    const float* b1  = (const float*)d_in[2];
    const float* w2  = (const float*)d_in[3];
    const float* b2  = (const float*)d_in[4];
    const float* w3  = (const float*)d_in[5];
    const float* b3  = (const float*)d_in[6];
    const float* gw1 = (const float*)d_in[7];
    const float* gw2 = (const float*)d_in[8];
    const float* rot = (const float*)d_in[9];
    const float* ent = (const float*)d_in[10];
    const float* rw  = (const float*)d_in[11];
    const float* rbv = (const float*)d_in[12];
    const float* cw  = (const float*)d_in[13];
    const float* cbv = (const float*)d_in[14];
    const float* gam = (const float*)d_in[15];
    const float* bet = (const float*)d_in[16];

    const int B = in_sizes[0] / (32 * 32);   // 4096

    _Float16* q16  = (_Float16*)d_ws;                 // [B][16]
    _Float16* k16  = q16 + (size_t)B * 16;            // [B][16]
    _Float16* g16  = k16 + (size_t)B * 16;            // [B][16]
    _Float16* gswz = g16 + (size_t)B * 16;            // [B/16][64][4]
    _Float16* w2f  = gswz + (size_t)B * 16;           // 1536 halves
    _Float16* w3f  = w2f + 1536;                      // 5120 halves
    h2v*      w1p  = (h2v*)(w3f + 5120);              // 24 pairs
    float*    w1t  = (float*)(w1p + 24);              // 24 floats
    float* pre = (float*)d_out;

    k_pack<<<1, 256, 0, stream>>>(w1, w2, w3, w2f, w3f, w1p, w1t);
    k_cnn<<<B, 256, 0, stream>>>(x, w1p, w1t, b1, w2f, b2, w3f, b3, gw1, gw2,
                                 rot, ent, q16, k16, g16, gswz);
    k_attn<<<B / 16, 1024, 0, stream>>>(q16, k16, g16, gswz, rw, rbv, cw, cbv,
                                        pre, B);
    k_bn<<<1, 1024, 0, stream>>>(pre, gam, bet, B);
}